// Round 7
// baseline (53016.083 us; speedup 1.0000x reference)
//
#include <hip/hip_runtime.h>

typedef __attribute__((ext_vector_type(8))) short short8v;
typedef __attribute__((ext_vector_type(4))) float f32x4;

#define MFMA(a,b,c) __builtin_amdgcn_mfma_f32_16x16x32_bf16((a),(b),(c),0,0,0)
#define NB 256

__device__ __forceinline__ float rcpf_(float x){ return __builtin_amdgcn_rcpf(x); }
__device__ __forceinline__ float sigf(float x){ return rcpf_(1.0f + __expf(-x)); }
__device__ __forceinline__ float tanhfast(float x){ return fmaf(-2.0f, rcpf_(1.0f + __expf(2.0f*x)), 1.0f); }
__device__ __forceinline__ float bf2f(unsigned short u){ union{unsigned int i; float f;} v; v.i = ((unsigned int)u)<<16; return v.f; }
__device__ __forceinline__ float u2f(unsigned int i){ union{unsigned int i; float f;} v; v.i = i; return v.f; }
__device__ __forceinline__ unsigned short f2bf(float f){ union{float f; unsigned int i;} v; v.f=f; unsigned int x = v.i + 0x7fffu + ((v.i>>16)&1u); return (unsigned short)(x>>16); }
__device__ __forceinline__ float4 ld4(const float* p){ return *(const float4*)p; }

// grid barrier: monotonic counter, all 256 blocks resident (1 block/CU guaranteed by launch_bounds)
__device__ __forceinline__ void gbar(unsigned* cnt, unsigned target){
  __syncthreads();
  if (threadIdx.x == 0){
    __threadfence();
    __hip_atomic_fetch_add(cnt, 1u, __ATOMIC_RELEASE, __HIP_MEMORY_SCOPE_AGENT);
    while (__hip_atomic_load(cnt, __ATOMIC_ACQUIRE, __HIP_MEMORY_SCOPE_AGENT) < target)
      __builtin_amdgcn_s_sleep(2);
  }
  __syncthreads();
}

// ============ prep kernels (proven) ============
__global__ __launch_bounds__(256) void k_w1(const float* __restrict__ iw1, const float* __restrict__ hw1,
                                            ushort* __restrict__ w1b){
  int idx4 = (blockIdx.x*256 + threadIdx.x) * 4;
  int n = idx4 / 1536, k = idx4 % 1536;
  float4 v = (k < 512) ? *(const float4*)(iw1 + n*512 + k)
                       : *(const float4*)(hw1 + n*1024 + (k - 512));
  ushort4 o; o.x=f2bf(v.x); o.y=f2bf(v.y); o.z=f2bf(v.z); o.w=f2bf(v.w);
  *(ushort4*)(w1b + idx4) = o;
}
__global__ __launch_bounds__(256) void k_w2(const float* __restrict__ h2a, const float* __restrict__ hw2,
                                            ushort* __restrict__ w2b){
  int idx4 = (blockIdx.x*256 + threadIdx.x) * 4;
  int n = idx4 >> 10, k = idx4 & 1023;
  float4 v = (n < 1024) ? *(const float4*)(h2a + n*1024 + k)
                        : *(const float4*)(hw2 + (n-1024)*1024 + k);
  ushort4 o; o.x=f2bf(v.x); o.y=f2bf(v.y); o.z=f2bf(v.z); o.w=f2bf(v.w);
  *(ushort4*)(w2b + idx4) = o;
}
__global__ __launch_bounds__(256) void k_w3(const float* __restrict__ iw2, ushort* __restrict__ w3b){
  int idx4 = (blockIdx.x*256 + threadIdx.x) * 4;
  float4 v = *(const float4*)(iw2 + idx4);
  ushort4 o; o.x=f2bf(v.x); o.y=f2bf(v.y); o.z=f2bf(v.z); o.w=f2bf(v.w);
  *(ushort4*)(w3b + idx4) = o;
}
__global__ __launch_bounds__(256) void k_ctxT(const float* __restrict__ ctx, ushort* __restrict__ ctxb){
  int idx4 = (blockIdx.x*256 + threadIdx.x) * 4;
  int c = idx4 & 1023, s = (idx4 >> 10) & 255, b = idx4 >> 18;
  float4 v = *(const float4*)(ctx + (s*64 + b)*1024 + c);
  ushort4 o; o.x=f2bf(v.x); o.y=f2bf(v.y); o.z=f2bf(v.z); o.w=f2bf(v.w);
  *(ushort4*)(ctxb + idx4) = o;
}
__global__ __launch_bounds__(256) void k_xb(const float* __restrict__ inp, ushort* __restrict__ xb){
  int idx4 = (blockIdx.x*256 + threadIdx.x) * 4;
  int k = idx4 & 511, b = (idx4 >> 9) & 63, t = idx4 >> 15;
  float4 v = *(const float4*)(inp + (b*256 + t)*512 + k);
  ushort4 o; o.x=f2bf(v.x); o.y=f2bf(v.y); o.z=f2bf(v.z); o.w=f2bf(v.w);
  *(ushort4*)(xb + idx4) = o;
}
__global__ __launch_bounds__(256) void k_i2aT(const float* __restrict__ i2a, ushort* __restrict__ i2aT){
  int idx = blockIdx.x*256 + threadIdx.x;
  int n = idx & 1023, k = idx >> 10;
  i2aT[n*512 + k] = f2bf(i2a[k*1024 + n]);
}
__global__ __launch_bounds__(256) void k_cvthx(const float* __restrict__ hx, ushort* __restrict__ hxbbf){
  int i4 = (blockIdx.x*256 + threadIdx.x)*4;
  float4 v = ld4(hx + i4);
  ushort4 o; o.x=f2bf(v.x); o.y=f2bf(v.y); o.z=f2bf(v.z); o.w=f2bf(v.w);
  *(ushort4*)(hxbbf + i4) = o;
}
__global__ __launch_bounds__(256) void k_bias(const float* __restrict__ ib1, const float* __restrict__ hb1,
                                              const float* __restrict__ ib2, const float* __restrict__ hb2,
                                              float* __restrict__ b1s, float* __restrict__ b2s){
  int i = blockIdx.x*256 + threadIdx.x;
  b1s[i] = ib1[i] + hb1[i];
  b2s[i] = ib2[i] + hb2[i];
}

__global__ __launch_bounds__(256) void k_pc(const float* __restrict__ ctxp, const float* __restrict__ c2a,
                                            const float* __restrict__ bc, ushort* __restrict__ pcb){
  __shared__ __align__(16) float As[32][68];
  __shared__ __align__(16) float Bs[32][68];
  const int tid = threadIdx.x;
  const int m0 = blockIdx.x * 64;
  const int n0 = blockIdx.y * 64;
  const int tx = tid & 15, ty = tid >> 4;
  float acc[4][4] = {};
  for (int k0 = 0; k0 < 1024; k0 += 32){
#pragma unroll
    for (int l = 0; l < 8; ++l){
      int idx = l*256 + tid; int m = idx >> 5, k = idx & 31;
      As[k][m] = ctxp[(m0+m)*1024 + k0 + k];
    }
#pragma unroll
    for (int l = 0; l < 8; ++l){
      int idx = l*256 + tid; int k = idx >> 6, n = idx & 63;
      Bs[k][n] = c2a[(k0+k)*1024 + n0 + n];
    }
    __syncthreads();
#pragma unroll
    for (int k = 0; k < 32; ++k){
      float4 a4 = *(const float4*)&As[k][4*ty];
      float4 b4 = *(const float4*)&Bs[k][4*tx];
      float av[4] = {a4.x, a4.y, a4.z, a4.w};
      float bv[4] = {b4.x, b4.y, b4.z, b4.w};
#pragma unroll
      for (int i = 0; i < 4; ++i)
#pragma unroll
        for (int j = 0; j < 4; ++j) acc[i][j] = fmaf(av[i], bv[j], acc[i][j]);
    }
    __syncthreads();
  }
#pragma unroll
  for (int i = 0; i < 4; ++i){
    int m = m0 + 4*ty + i;
    int n = n0 + 4*tx;
    ushort4 o;
    o.x = f2bf(acc[i][0] + bc[n]);
    o.y = f2bf(acc[i][1] + bc[n+1]);
    o.z = f2bf(acc[i][2] + bc[n+2]);
    o.w = f2bf(acc[i][3] + bc[n+3]);
    *(ushort4*)(pcb + m*1024 + n) = o;
  }
}

// ============ THE persistent scan kernel: 256 blocks x 512 thr ============
__global__ __launch_bounds__(512, 2) void k_fused(
    const ushort* __restrict__ xb, const ushort* __restrict__ w1b,
    const ushort* __restrict__ w2b, const ushort* __restrict__ w3b,
    const ushort* __restrict__ i2aT, const ushort* __restrict__ pcb,
    const ushort* __restrict__ ctxb, const float* __restrict__ r2a,
    const float* __restrict__ b1s, const float* __restrict__ b2s,
    float* __restrict__ hyp, float* __restrict__ cym,
    float* __restrict__ cxb, float* __restrict__ hxb,
    ushort* __restrict__ hybf, ushort* __restrict__ hxbbf,
    ushort* __restrict__ wctxbf, float* __restrict__ logits,
    float* __restrict__ out, unsigned* __restrict__ barcnt)
{
  __shared__ float lred[2][64][17];
  __shared__ float al[256];
  __shared__ float red[256];
  __shared__ float4 part4[8][64];
  const int tid = threadIdx.x;
  const int bid = blockIdx.x;
  const int lane = tid & 63;
  const int w = tid >> 6;
  const int strip = w & 3;
  const int kh = w >> 2;
  const int ko = (lane >> 4) << 3;
  const int cc = lane & 15;
  unsigned bu = 0;

  for (int t = 0; t < 256; ++t){
    // ---------- Phase A: gates1 (4 gates x 4 h-cols per block) + LSTM1 ----------
    {
      const int g = cc >> 2;
      const int ncol = (g << 10) + (bid << 2) + (cc & 3);
      const int arow = strip*16 + cc;
      const ushort* wp = w1b + ncol*1536 + kh*768 + ko;
      f32x4 a = {0.f,0.f,0.f,0.f};
      if (kh == 0){
        const ushort* xp = xb + (t*64 + arow)*512 + ko;
#pragma unroll
        for (int it = 0; it < 16; ++it)
          a = MFMA(*(const short8v*)(xp + it*32), *(const short8v*)(wp + it*32), a);
        const ushort* hp = hxbbf + arow*1024 + ko;
#pragma unroll
        for (int it = 0; it < 8; ++it)
          a = MFMA(*(const short8v*)(hp + it*32), *(const short8v*)(wp + (16+it)*32), a);
      } else {
        const ushort* hp = hxbbf + arow*1024 + 256 + ko;
#pragma unroll
        for (int it = 0; it < 24; ++it)
          a = MFMA(*(const short8v*)(hp + it*32), *(const short8v*)(wp + it*32), a);
      }
      const int rb = strip*16 + ((lane >> 4) << 2);
#pragma unroll
      for (int r = 0; r < 4; ++r) lred[kh][rb + r][cc] = a[r];
    }
    __syncthreads();
    if (tid < 256){
      const int row = tid >> 2, hi = tid & 3, hh = (bid << 2) + hi;
      float gi = lred[0][row][hi]      + lred[1][row][hi]      + b1s[hh];
      float gf = lred[0][row][4+hi]    + lred[1][row][4+hi]    + b1s[1024+hh];
      float gg = lred[0][row][8+hi]    + lred[1][row][8+hi]    + b1s[2048+hh];
      float go = lred[0][row][12+hi]   + lred[1][row][12+hi]   + b1s[3072+hh];
      float c1 = sigf(gf)*cxb[row*1024+hh] + sigf(gi)*tanhfast(gg);
      cym[row*1024+hh] = c1;
      hybf[row*1024+hh] = f2bf(sigf(go)*tanhfast(c1));
    }
    ++bu; gbar(barcnt, bu*NB);

    // ---------- Phase B: hyproj (N=5120, 320 tiles of 16) + i2a fold ----------
    for (int tt = bid; tt < 320; tt += 256){
      const int ncol = tt*16 + cc;
      const int arow = strip*16 + cc;
      const ushort* wp = w2b + ncol*1024 + kh*512 + ko;
      const ushort* hp = hybf + arow*1024 + kh*512 + ko;
      f32x4 a = {0.f,0.f,0.f,0.f};
#pragma unroll
      for (int it = 0; it < 16; ++it)
        a = MFMA(*(const short8v*)(hp + it*32), *(const short8v*)(wp + it*32), a);
      if (tt < 64){
        const ushort* ip = i2aT + ncol*512 + kh*256 + ko;
        const ushort* xp = xb + (t*64 + arow)*512 + kh*256 + ko;
#pragma unroll
        for (int it = 0; it < 8; ++it)
          a = MFMA(*(const short8v*)(xp + it*32), *(const short8v*)(ip + it*32), a);
      }
      const int rb = strip*16 + ((lane >> 4) << 2);
#pragma unroll
      for (int r = 0; r < 4; ++r) lred[kh][rb + r][cc] = a[r];
      __syncthreads();
#pragma unroll
      for (int e = tid; e < 1024; e += 512){
        int row = e >> 4, c2 = e & 15;
        hyp[row*5120 + tt*16 + c2] = lred[0][row][c2] + lred[1][row][c2];
      }
      __syncthreads();
    }
    ++bu; gbar(barcnt, bu*NB);

    // ---------- Phase C: logits (2048 waves, 8 s each) ----------
    {
      const int gw = bid*8 + w;
      const int b = gw >> 5;
      const int sg = gw & 31;
      const float* qp = hyp + b*5120 + lane*16;
      const float* rp = r2a + lane*16;
      float q[16], r[16];
#pragma unroll
      for (int i = 0; i < 4; ++i){
        float4 qv = ld4(qp + i*4);
        float4 rv = ld4(rp + i*4);
        q[4*i]=qv.x; q[4*i+1]=qv.y; q[4*i+2]=qv.z; q[4*i+3]=qv.w;
        r[4*i]=rv.x; r[4*i+1]=rv.y; r[4*i+2]=rv.z; r[4*i+3]=rv.w;
      }
#pragma unroll
      for (int pi = 0; pi < 8; ++pi){
        const int s = sg*8 + pi;
        const ushort* pp = pcb + (s*64 + b)*1024 + lane*16;
        uint4 v0 = *(const uint4*)pp;
        uint4 v1 = *(const uint4*)(pp + 8);
        float acc;
        acc  = tanhfast(u2f(v0.x << 16)              + q[0])  * r[0];
        acc  = fmaf(tanhfast(u2f(v0.x & 0xffff0000u) + q[1]),  r[1],  acc);
        acc  = fmaf(tanhfast(u2f(v0.y << 16)         + q[2]),  r[2],  acc);
        acc  = fmaf(tanhfast(u2f(v0.y & 0xffff0000u) + q[3]),  r[3],  acc);
        acc  = fmaf(tanhfast(u2f(v0.z << 16)         + q[4]),  r[4],  acc);
        acc  = fmaf(tanhfast(u2f(v0.z & 0xffff0000u) + q[5]),  r[5],  acc);
        acc  = fmaf(tanhfast(u2f(v0.w << 16)         + q[6]),  r[6],  acc);
        acc  = fmaf(tanhfast(u2f(v0.w & 0xffff0000u) + q[7]),  r[7],  acc);
        acc  = fmaf(tanhfast(u2f(v1.x << 16)         + q[8]),  r[8],  acc);
        acc  = fmaf(tanhfast(u2f(v1.x & 0xffff0000u) + q[9]),  r[9],  acc);
        acc  = fmaf(tanhfast(u2f(v1.y << 16)         + q[10]), r[10], acc);
        acc  = fmaf(tanhfast(u2f(v1.y & 0xffff0000u) + q[11]), r[11], acc);
        acc  = fmaf(tanhfast(u2f(v1.z << 16)         + q[12]), r[12], acc);
        acc  = fmaf(tanhfast(u2f(v1.z & 0xffff0000u) + q[13]), r[13], acc);
        acc  = fmaf(tanhfast(u2f(v1.w << 16)         + q[14]), r[14], acc);
        acc  = fmaf(tanhfast(u2f(v1.w & 0xffff0000u) + q[15]), r[15], acc);
#pragma unroll
        for (int off = 32; off; off >>= 1) acc += __shfl_xor(acc, off);
        if (lane == 0) logits[b*256 + s] = acc;
      }
    }
    ++bu; gbar(barcnt, bu*NB);

    // ---------- Phase D: softmax + weighted ctx (block = (b, 256-c slice)) ----------
    {
      const int b = bid >> 2, cq = bid & 3;
      if (tid < 256){ float l = logits[b*256 + tid]; red[tid] = l; al[tid] = l; }
      __syncthreads();
      for (int s = 128; s; s >>= 1){ if (tid < s) red[tid] = fmaxf(red[tid], red[tid+s]); __syncthreads(); }
      float mx = red[0]; __syncthreads();
      if (tid < 256){ float e = __expf(al[tid] - mx); al[tid] = e; red[tid] = e; }
      __syncthreads();
      for (int s = 128; s; s >>= 1){ if (tid < s) red[tid] += red[tid+s]; __syncthreads(); }
      float inv = rcpf_(red[0]);
      const int ci = tid & 63, sh = tid >> 6;
      const int c = cq*256 + ci*4;
      const ushort* cp = ctxb + (b*256 + sh*32)*1024 + c;
      float a0=0.f, a1=0.f, a2=0.f, a3=0.f;
#pragma unroll 8
      for (int s = 0; s < 32; ++s){
        ushort4 v = *(const ushort4*)(cp + s*1024);
        float aw = al[sh*32 + s];
        a0 = fmaf(aw, bf2f(v.x), a0);
        a1 = fmaf(aw, bf2f(v.y), a1);
        a2 = fmaf(aw, bf2f(v.z), a2);
        a3 = fmaf(aw, bf2f(v.w), a3);
      }
      part4[sh][ci] = make_float4(a0, a1, a2, a3);
      __syncthreads();
      if (tid < 256){
        const float* pf = (const float*)part4;
        float s0 = 0.f;
#pragma unroll
        for (int s2 = 0; s2 < 8; ++s2) s0 += pf[s2*256 + tid];
        wctxbf[b*1024 + cq*256 + tid] = f2bf(s0 * inv);
      }
    }
    ++bu; gbar(barcnt, bu*NB);

    // ---------- Phase E: gates2 (4 gates x 4 h-cols) + LSTM2 ----------
    {
      const int g = cc >> 2;
      const int ncol = (g << 10) + (bid << 2) + (cc & 3);
      const int arow = strip*16 + cc;
      const ushort* wp = w3b + ncol*1024 + kh*512 + ko;
      const ushort* ap = wctxbf + arow*1024 + kh*512 + ko;
      f32x4 a = {0.f,0.f,0.f,0.f};
#pragma unroll
      for (int it = 0; it < 16; ++it)
        a = MFMA(*(const short8v*)(ap + it*32), *(const short8v*)(wp + it*32), a);
      const int rb = strip*16 + ((lane >> 4) << 2);
#pragma unroll
      for (int r = 0; r < 4; ++r) lred[kh][rb + r][cc] = a[r];
    }
    __syncthreads();
    if (tid < 256){
      const int row = tid >> 2, hi = tid & 3, hh = (bid << 2) + hi;
      const float* g2 = hyp + row*5120 + 1024;
      float gi = lred[0][row][hi]      + lred[1][row][hi]      + g2[hh]      + b2s[hh];
      float gf = lred[0][row][4+hi]    + lred[1][row][4+hi]    + g2[1024+hh] + b2s[1024+hh];
      float gg = lred[0][row][8+hi]    + lred[1][row][8+hi]    + g2[2048+hh] + b2s[2048+hh];
      float go = lred[0][row][12+hi]   + lred[1][row][12+hi]   + g2[3072+hh] + b2s[3072+hh];
      float c2 = sigf(gf)*cym[row*1024+hh] + sigf(gi)*tanhfast(gg);
      float hv = sigf(go)*tanhfast(c2);
      out[t*65536 + row*1024 + hh] = hv;
      cxb[row*1024+hh] = c2;
      hxb[row*1024+hh] = hv;
      hxbbf[row*1024+hh] = f2bf(hv);
    }
    ++bu; gbar(barcnt, bu*NB);
  }
}

extern "C" void kernel_launch(void* const* d_in, const int* in_sizes, int n_in,
                              void* d_out, int out_size, void* d_ws, size_t ws_size,
                              hipStream_t stream) {
  const float* input = (const float*)d_in[0];
  const float* hx    = (const float*)d_in[1];
  const float* cx    = (const float*)d_in[2];
  const float* ctxp  = (const float*)d_in[3];
  const float* iw1   = (const float*)d_in[4];
  const float* hw1   = (const float*)d_in[5];
  const float* ib1   = (const float*)d_in[6];
  const float* hb1   = (const float*)d_in[7];
  const float* iw2   = (const float*)d_in[8];
  const float* hw2   = (const float*)d_in[9];
  const float* ib2   = (const float*)d_in[10];
  const float* hb2   = (const float*)d_in[11];
  const float* c2a   = (const float*)d_in[12];
  const float* b_c2a = (const float*)d_in[13];
  const float* h2a   = (const float*)d_in[14];
  const float* i2a   = (const float*)d_in[15];
  const float* r2a   = (const float*)d_in[16];
  float* out = (float*)d_out;

  char* base = (char*)d_ws;
  ushort* pcb    = (ushort*)(base);                     // 33,554,432
  ushort* ctxb   = (ushort*)(base + 33554432);          // 33,554,432
  ushort* xb     = (ushort*)(base + 67108864);          // 16,777,216
  ushort* w1b    = (ushort*)(base + 83886080);          // 12,582,912
  ushort* w2b    = (ushort*)(base + 96468992);          // 10,485,760
  ushort* w3b    = (ushort*)(base + 106954752);         //  8,388,608
  ushort* i2aT   = (ushort*)(base + 115343360);         //  1,048,576
  float*  hyp    = (float*)(base + 116391936);          //  1,310,720
  float*  cym    = (float*)(base + 117702656);          //    262,144
  float*  hxb    = (float*)(base + 117964800);          //    262,144
  float*  cxb    = (float*)(base + 118226944);          //    262,144
  ushort* hybf   = (ushort*)(base + 118489088);         //    131,072
  ushort* hxbbf  = (ushort*)(base + 118620160);         //    131,072
  ushort* wctxbf = (ushort*)(base + 118751232);         //    131,072
  float*  logits = (float*)(base + 118882304);          //     65,536
  float*  b1s    = (float*)(base + 118947840);          //     16,384
  float*  b2s    = (float*)(base + 118964224);          //     16,384
  unsigned* barcnt = (unsigned*)(base + 118980608);     //        256

  hipMemsetAsync(barcnt, 0, 256, stream);
  hipMemcpyAsync(hxb, hx, 262144, hipMemcpyDeviceToDevice, stream);
  hipMemcpyAsync(cxb, cx, 262144, hipMemcpyDeviceToDevice, stream);

  k_cvthx<<<64,   256, 0, stream>>>(hx, hxbbf);
  k_bias<<<16,    256, 0, stream>>>(ib1, hb1, ib2, hb2, b1s, b2s);
  k_w1  <<<6144,  256, 0, stream>>>(iw1, hw1, w1b);
  k_w2  <<<5120,  256, 0, stream>>>(h2a, hw2, w2b);
  k_w3  <<<4096,  256, 0, stream>>>(iw2, w3b);
  k_ctxT<<<16384, 256, 0, stream>>>(ctxp, ctxb);
  k_xb  <<<8192,  256, 0, stream>>>(input, xb);
  k_i2aT<<<2048,  256, 0, stream>>>(i2a, i2aT);
  k_pc  <<<dim3(256,16), 256, 0, stream>>>(ctxp, c2a, b_c2a, pcb);

  k_fused<<<NB, 512, 0, stream>>>(xb, w1b, w2b, w3b, i2aT, pcb, ctxb, r2a,
                                  b1s, b2s, hyp, cym, cxb, hxb, hybf, hxbbf,
                                  wctxbf, logits, out, barcnt);

  hipMemcpyAsync(out + 16777216,         hxb, 262144, hipMemcpyDeviceToDevice, stream);
  hipMemcpyAsync(out + 16777216 + 65536, cxb, 262144, hipMemcpyDeviceToDevice, stream);
}

// Round 8
// 25638.651 us; speedup vs baseline: 2.0678x; 2.0678x over previous
//
#include <hip/hip_runtime.h>

typedef __attribute__((ext_vector_type(8))) short short8v;
typedef __attribute__((ext_vector_type(4))) float f32x4;

#define MFMA(a,b,c) __builtin_amdgcn_mfma_f32_16x16x32_bf16((a),(b),(c),0,0,0)
#define NB 256

__device__ __forceinline__ float rcpf_(float x){ return __builtin_amdgcn_rcpf(x); }
__device__ __forceinline__ float sigf(float x){ return rcpf_(1.0f + __expf(-x)); }
__device__ __forceinline__ float tanhfast(float x){ return fmaf(-2.0f, rcpf_(1.0f + __expf(2.0f*x)), 1.0f); }
__device__ __forceinline__ float bf2f(unsigned short u){ union{unsigned int i; float f;} v; v.i = ((unsigned int)u)<<16; return v.f; }
__device__ __forceinline__ float u2f(unsigned int i){ union{unsigned int i; float f;} v; v.i = i; return v.f; }
__device__ __forceinline__ unsigned short f2bf(float f){ union{float f; unsigned int i;} v; v.f=f; unsigned int x = v.i + 0x7fffu + ((v.i>>16)&1u); return (unsigned short)(x>>16); }
__device__ __forceinline__ float4 ld4(const float* p){ return *(const float4*)p; }

// ---- coherent (L2-bypass) access helpers: sc0 sc1 => read/write at the coherence point,
// ---- no L2 allocation, hence NO cache invalidates needed anywhere in the persistent kernel.
struct V8 { short8v v0,v1,v2,v3,v4,v5,v6,v7; };
__device__ __forceinline__ V8 ldg8(const ushort* p){
  V8 r;
  asm volatile(
    "global_load_dwordx4 %0, %8, off sc0 sc1\n\t"
    "global_load_dwordx4 %1, %8, off offset:64 sc0 sc1\n\t"
    "global_load_dwordx4 %2, %8, off offset:128 sc0 sc1\n\t"
    "global_load_dwordx4 %3, %8, off offset:192 sc0 sc1\n\t"
    "global_load_dwordx4 %4, %8, off offset:256 sc0 sc1\n\t"
    "global_load_dwordx4 %5, %8, off offset:320 sc0 sc1\n\t"
    "global_load_dwordx4 %6, %8, off offset:384 sc0 sc1\n\t"
    "global_load_dwordx4 %7, %8, off offset:448 sc0 sc1\n\t"
    "s_waitcnt vmcnt(0)"
    : "=v"(r.v0),"=v"(r.v1),"=v"(r.v2),"=v"(r.v3),"=v"(r.v4),"=v"(r.v5),"=v"(r.v6),"=v"(r.v7)
    : "v"(p));
  return r;
}
__device__ __forceinline__ void ldg4f(const float* p, f32x4& a, f32x4& b, f32x4& c, f32x4& d){
  asm volatile(
    "global_load_dwordx4 %0, %4, off sc0 sc1\n\t"
    "global_load_dwordx4 %1, %4, off offset:16 sc0 sc1\n\t"
    "global_load_dwordx4 %2, %4, off offset:32 sc0 sc1\n\t"
    "global_load_dwordx4 %3, %4, off offset:48 sc0 sc1\n\t"
    "s_waitcnt vmcnt(0)"
    : "=v"(a),"=v"(b),"=v"(c),"=v"(d) : "v"(p));
}
__device__ __forceinline__ void ldg4s(const float* p0, const float* p1, const float* p2, const float* p3,
                                      float& a, float& b, float& c, float& d){
  asm volatile(
    "global_load_dword %0, %4, off sc0 sc1\n\t"
    "global_load_dword %1, %5, off sc0 sc1\n\t"
    "global_load_dword %2, %6, off sc0 sc1\n\t"
    "global_load_dword %3, %7, off sc0 sc1\n\t"
    "s_waitcnt vmcnt(0)"
    : "=v"(a),"=v"(b),"=v"(c),"=v"(d) : "v"(p0),"v"(p1),"v"(p2),"v"(p3));
}
__device__ __forceinline__ float ldg1f(const float* p){
  float r;
  asm volatile("global_load_dword %0, %1, off sc0 sc1\n\ts_waitcnt vmcnt(0)" : "=v"(r) : "v"(p));
  return r;
}
__device__ __forceinline__ void stg_f32(float* p, float v){
  asm volatile("global_store_dword %0, %1, off sc0 sc1" :: "v"(p), "v"(v) : "memory");
}
__device__ __forceinline__ void stg_u16(ushort* p, unsigned v){
  asm volatile("global_store_short %0, %1, off sc0 sc1" :: "v"(p), "v"(v) : "memory");
}

// grid barrier: RELAXED atomics only — never emits buffer_inv, L2 stays warm.
// visibility: every thread drains vmcnt before s_barrier; leader's add at IC happens after.
__device__ __forceinline__ void gbar(unsigned* cnt, unsigned target){
  asm volatile("s_waitcnt vmcnt(0) lgkmcnt(0)" ::: "memory");
  __syncthreads();
  if (threadIdx.x == 0){
    __hip_atomic_fetch_add(cnt, 1u, __ATOMIC_RELAXED, __HIP_MEMORY_SCOPE_AGENT);
    while (__hip_atomic_load(cnt, __ATOMIC_RELAXED, __HIP_MEMORY_SCOPE_AGENT) < target)
      __builtin_amdgcn_s_sleep(4);
  }
  __syncthreads();
}

// ============ prep kernels (proven) ============
__global__ __launch_bounds__(256) void k_w1(const float* __restrict__ iw1, const float* __restrict__ hw1,
                                            ushort* __restrict__ w1b){
  int idx4 = (blockIdx.x*256 + threadIdx.x) * 4;
  int n = idx4 / 1536, k = idx4 % 1536;
  float4 v = (k < 512) ? *(const float4*)(iw1 + n*512 + k)
                       : *(const float4*)(hw1 + n*1024 + (k - 512));
  ushort4 o; o.x=f2bf(v.x); o.y=f2bf(v.y); o.z=f2bf(v.z); o.w=f2bf(v.w);
  *(ushort4*)(w1b + idx4) = o;
}
__global__ __launch_bounds__(256) void k_w2(const float* __restrict__ h2a, const float* __restrict__ hw2,
                                            ushort* __restrict__ w2b){
  int idx4 = (blockIdx.x*256 + threadIdx.x) * 4;
  int n = idx4 >> 10, k = idx4 & 1023;
  float4 v = (n < 1024) ? *(const float4*)(h2a + n*1024 + k)
                        : *(const float4*)(hw2 + (n-1024)*1024 + k);
  ushort4 o; o.x=f2bf(v.x); o.y=f2bf(v.y); o.z=f2bf(v.z); o.w=f2bf(v.w);
  *(ushort4*)(w2b + idx4) = o;
}
__global__ __launch_bounds__(256) void k_w3(const float* __restrict__ iw2, ushort* __restrict__ w3b){
  int idx4 = (blockIdx.x*256 + threadIdx.x) * 4;
  float4 v = *(const float4*)(iw2 + idx4);
  ushort4 o; o.x=f2bf(v.x); o.y=f2bf(v.y); o.z=f2bf(v.z); o.w=f2bf(v.w);
  *(ushort4*)(w3b + idx4) = o;
}
__global__ __launch_bounds__(256) void k_ctxT(const float* __restrict__ ctx, ushort* __restrict__ ctxb){
  int idx4 = (blockIdx.x*256 + threadIdx.x) * 4;
  int c = idx4 & 1023, s = (idx4 >> 10) & 255, b = idx4 >> 18;
  float4 v = *(const float4*)(ctx + (s*64 + b)*1024 + c);
  ushort4 o; o.x=f2bf(v.x); o.y=f2bf(v.y); o.z=f2bf(v.z); o.w=f2bf(v.w);
  *(ushort4*)(ctxb + idx4) = o;
}
__global__ __launch_bounds__(256) void k_xb(const float* __restrict__ inp, ushort* __restrict__ xb){
  int idx4 = (blockIdx.x*256 + threadIdx.x) * 4;
  int k = idx4 & 511, b = (idx4 >> 9) & 63, t = idx4 >> 15;
  float4 v = *(const float4*)(inp + (b*256 + t)*512 + k);
  ushort4 o; o.x=f2bf(v.x); o.y=f2bf(v.y); o.z=f2bf(v.z); o.w=f2bf(v.w);
  *(ushort4*)(xb + idx4) = o;
}
__global__ __launch_bounds__(256) void k_i2aT(const float* __restrict__ i2a, ushort* __restrict__ i2aT){
  int idx = blockIdx.x*256 + threadIdx.x;
  int n = idx & 1023, k = idx >> 10;
  i2aT[n*512 + k] = f2bf(i2a[k*1024 + n]);
}
__global__ __launch_bounds__(256) void k_cvthx(const float* __restrict__ hx, ushort* __restrict__ hxbbf){
  int i4 = (blockIdx.x*256 + threadIdx.x)*4;
  float4 v = ld4(hx + i4);
  ushort4 o; o.x=f2bf(v.x); o.y=f2bf(v.y); o.z=f2bf(v.z); o.w=f2bf(v.w);
  *(ushort4*)(hxbbf + i4) = o;
}
__global__ __launch_bounds__(256) void k_bias(const float* __restrict__ ib1, const float* __restrict__ hb1,
                                              const float* __restrict__ ib2, const float* __restrict__ hb2,
                                              float* __restrict__ b1s, float* __restrict__ b2s){
  int i = blockIdx.x*256 + threadIdx.x;
  b1s[i] = ib1[i] + hb1[i];
  b2s[i] = ib2[i] + hb2[i];
}

__global__ __launch_bounds__(256) void k_pc(const float* __restrict__ ctxp, const float* __restrict__ c2a,
                                            const float* __restrict__ bc, ushort* __restrict__ pcb){
  __shared__ __align__(16) float As[32][68];
  __shared__ __align__(16) float Bs[32][68];
  const int tid = threadIdx.x;
  const int m0 = blockIdx.x * 64;
  const int n0 = blockIdx.y * 64;
  const int tx = tid & 15, ty = tid >> 4;
  float acc[4][4] = {};
  for (int k0 = 0; k0 < 1024; k0 += 32){
#pragma unroll
    for (int l = 0; l < 8; ++l){
      int idx = l*256 + tid; int m = idx >> 5, k = idx & 31;
      As[k][m] = ctxp[(m0+m)*1024 + k0 + k];
    }
#pragma unroll
    for (int l = 0; l < 8; ++l){
      int idx = l*256 + tid; int k = idx >> 6, n = idx & 63;
      Bs[k][n] = c2a[(k0+k)*1024 + n0 + n];
    }
    __syncthreads();
#pragma unroll
    for (int k = 0; k < 32; ++k){
      float4 a4 = *(const float4*)&As[k][4*ty];
      float4 b4 = *(const float4*)&Bs[k][4*tx];
      float av[4] = {a4.x, a4.y, a4.z, a4.w};
      float bv[4] = {b4.x, b4.y, b4.z, b4.w};
#pragma unroll
      for (int i = 0; i < 4; ++i)
#pragma unroll
        for (int j = 0; j < 4; ++j) acc[i][j] = fmaf(av[i], bv[j], acc[i][j]);
    }
    __syncthreads();
  }
#pragma unroll
  for (int i = 0; i < 4; ++i){
    int m = m0 + 4*ty + i;
    int n = n0 + 4*tx;
    ushort4 o;
    o.x = f2bf(acc[i][0] + bc[n]);
    o.y = f2bf(acc[i][1] + bc[n+1]);
    o.z = f2bf(acc[i][2] + bc[n+2]);
    o.w = f2bf(acc[i][3] + bc[n+3]);
    *(ushort4*)(pcb + m*1024 + n) = o;
  }
}

// ============ THE persistent scan kernel: 256 blocks x 512 thr ============
__global__ __launch_bounds__(512, 1) void k_fused(
    const ushort* __restrict__ xb, const ushort* __restrict__ w1b,
    const ushort* __restrict__ w2b, const ushort* __restrict__ w3b,
    const ushort* __restrict__ i2aT, const ushort* __restrict__ pcb,
    const ushort* __restrict__ ctxb, const float* __restrict__ r2a,
    const float* __restrict__ b1s, const float* __restrict__ b2s,
    float* __restrict__ hyp, float* __restrict__ cym,
    float* __restrict__ cxb, float* __restrict__ hxb,
    ushort* __restrict__ hybf, ushort* __restrict__ hxbbf,
    ushort* __restrict__ wctxbf, float* __restrict__ logits,
    float* __restrict__ out, unsigned* __restrict__ barcnt)
{
  __shared__ float lred[2][64][17];
  __shared__ float al[256];
  __shared__ float red[256];
  __shared__ float4 part4[8][64];
  const int tid = threadIdx.x;
  const int bid = blockIdx.x;
  const int lane = tid & 63;
  const int w = tid >> 6;
  const int strip = w & 3;
  const int kh = w >> 2;
  const int ko = (lane >> 4) << 3;
  const int cc = lane & 15;
  unsigned bu = 0;

  for (int t = 0; t < 256; ++t){
    // ---------- Phase A: gates1 (4 gates x 4 h-cols per block) + LSTM1 ----------
    {
      const int g = cc >> 2;
      const int ncol = (g << 10) + (bid << 2) + (cc & 3);
      const int arow = strip*16 + cc;
      const ushort* wp = w1b + ncol*1536 + kh*768 + ko;
      f32x4 a = {0.f,0.f,0.f,0.f};
      if (kh == 0){
        const ushort* xp = xb + (t*64 + arow)*512 + ko;       // read-only: cached
#pragma unroll
        for (int it = 0; it < 16; ++it)
          a = MFMA(*(const short8v*)(xp + it*32), *(const short8v*)(wp + it*32), a);
        V8 h8 = ldg8(hxbbf + arow*1024 + ko);                 // mutable: bypass
        a = MFMA(h8.v0, *(const short8v*)(wp + 16*32), a);
        a = MFMA(h8.v1, *(const short8v*)(wp + 17*32), a);
        a = MFMA(h8.v2, *(const short8v*)(wp + 18*32), a);
        a = MFMA(h8.v3, *(const short8v*)(wp + 19*32), a);
        a = MFMA(h8.v4, *(const short8v*)(wp + 20*32), a);
        a = MFMA(h8.v5, *(const short8v*)(wp + 21*32), a);
        a = MFMA(h8.v6, *(const short8v*)(wp + 22*32), a);
        a = MFMA(h8.v7, *(const short8v*)(wp + 23*32), a);
      } else {
        const ushort* hp = hxbbf + arow*1024 + 256 + ko;
        V8 b0 = ldg8(hp);
        a = MFMA(b0.v0, *(const short8v*)(wp + 0*32), a);
        a = MFMA(b0.v1, *(const short8v*)(wp + 1*32), a);
        a = MFMA(b0.v2, *(const short8v*)(wp + 2*32), a);
        a = MFMA(b0.v3, *(const short8v*)(wp + 3*32), a);
        a = MFMA(b0.v4, *(const short8v*)(wp + 4*32), a);
        a = MFMA(b0.v5, *(const short8v*)(wp + 5*32), a);
        a = MFMA(b0.v6, *(const short8v*)(wp + 6*32), a);
        a = MFMA(b0.v7, *(const short8v*)(wp + 7*32), a);
        V8 b1 = ldg8(hp + 256);
        a = MFMA(b1.v0, *(const short8v*)(wp + 8*32), a);
        a = MFMA(b1.v1, *(const short8v*)(wp + 9*32), a);
        a = MFMA(b1.v2, *(const short8v*)(wp + 10*32), a);
        a = MFMA(b1.v3, *(const short8v*)(wp + 11*32), a);
        a = MFMA(b1.v4, *(const short8v*)(wp + 12*32), a);
        a = MFMA(b1.v5, *(const short8v*)(wp + 13*32), a);
        a = MFMA(b1.v6, *(const short8v*)(wp + 14*32), a);
        a = MFMA(b1.v7, *(const short8v*)(wp + 15*32), a);
        V8 b2 = ldg8(hp + 512);
        a = MFMA(b2.v0, *(const short8v*)(wp + 16*32), a);
        a = MFMA(b2.v1, *(const short8v*)(wp + 17*32), a);
        a = MFMA(b2.v2, *(const short8v*)(wp + 18*32), a);
        a = MFMA(b2.v3, *(const short8v*)(wp + 19*32), a);
        a = MFMA(b2.v4, *(const short8v*)(wp + 20*32), a);
        a = MFMA(b2.v5, *(const short8v*)(wp + 21*32), a);
        a = MFMA(b2.v6, *(const short8v*)(wp + 22*32), a);
        a = MFMA(b2.v7, *(const short8v*)(wp + 23*32), a);
      }
      const int rb = strip*16 + ((lane >> 4) << 2);
#pragma unroll
      for (int r = 0; r < 4; ++r) lred[kh][rb + r][cc] = a[r];
    }
    __syncthreads();
    if (tid < 256){
      const int row = tid >> 2, hi = tid & 3, hh = (bid << 2) + hi;
      float gi = lred[0][row][hi]      + lred[1][row][hi]      + b1s[hh];
      float gf = lred[0][row][4+hi]    + lred[1][row][4+hi]    + b1s[1024+hh];
      float gg = lred[0][row][8+hi]    + lred[1][row][8+hi]    + b1s[2048+hh];
      float go = lred[0][row][12+hi]   + lred[1][row][12+hi]   + b1s[3072+hh];
      float c1 = sigf(gf)*cxb[row*1024+hh] + sigf(gi)*tanhfast(gg);   // cxb: same-block, cached
      cym[row*1024+hh] = c1;                                          // same-block consumer
      stg_u16(hybf + row*1024 + hh, (unsigned)f2bf(sigf(go)*tanhfast(c1)));
    }
    ++bu; gbar(barcnt, bu*NB);

    // ---------- Phase B: hyproj (N=5120, 320 tiles of 16) + i2a fold ----------
    for (int tt = bid; tt < 320; tt += 256){
      const int ncol = tt*16 + cc;
      const int arow = strip*16 + cc;
      const ushort* wp = w2b + ncol*1024 + kh*512 + ko;
      const ushort* hp = hybf + arow*1024 + kh*512 + ko;
      f32x4 a = {0.f,0.f,0.f,0.f};
      V8 b0 = ldg8(hp);
      a = MFMA(b0.v0, *(const short8v*)(wp + 0*32), a);
      a = MFMA(b0.v1, *(const short8v*)(wp + 1*32), a);
      a = MFMA(b0.v2, *(const short8v*)(wp + 2*32), a);
      a = MFMA(b0.v3, *(const short8v*)(wp + 3*32), a);
      a = MFMA(b0.v4, *(const short8v*)(wp + 4*32), a);
      a = MFMA(b0.v5, *(const short8v*)(wp + 5*32), a);
      a = MFMA(b0.v6, *(const short8v*)(wp + 6*32), a);
      a = MFMA(b0.v7, *(const short8v*)(wp + 7*32), a);
      V8 b1 = ldg8(hp + 256);
      a = MFMA(b1.v0, *(const short8v*)(wp + 8*32), a);
      a = MFMA(b1.v1, *(const short8v*)(wp + 9*32), a);
      a = MFMA(b1.v2, *(const short8v*)(wp + 10*32), a);
      a = MFMA(b1.v3, *(const short8v*)(wp + 11*32), a);
      a = MFMA(b1.v4, *(const short8v*)(wp + 12*32), a);
      a = MFMA(b1.v5, *(const short8v*)(wp + 13*32), a);
      a = MFMA(b1.v6, *(const short8v*)(wp + 14*32), a);
      a = MFMA(b1.v7, *(const short8v*)(wp + 15*32), a);
      if (tt < 64){
        const ushort* ip = i2aT + ncol*512 + kh*256 + ko;     // read-only: cached
        const ushort* xp = xb + (t*64 + arow)*512 + kh*256 + ko;
#pragma unroll
        for (int it = 0; it < 8; ++it)
          a = MFMA(*(const short8v*)(xp + it*32), *(const short8v*)(ip + it*32), a);
      }
      const int rb = strip*16 + ((lane >> 4) << 2);
#pragma unroll
      for (int r = 0; r < 4; ++r) lred[kh][rb + r][cc] = a[r];
      __syncthreads();
#pragma unroll
      for (int e = tid; e < 1024; e += 512){
        int row = e >> 4, c2 = e & 15;
        stg_f32(hyp + row*5120 + tt*16 + c2, lred[0][row][c2] + lred[1][row][c2]);
      }
      __syncthreads();
    }
    ++bu; gbar(barcnt, bu*NB);

    // ---------- Phase C: logits (2048 waves, 8 s each) ----------
    {
      const int b = bid >> 2;
      const int sg = ((bid & 3) << 3) + w;
      const float* qp = hyp + b*5120 + lane*16;
      const float* rp = r2a + lane*16;
      f32x4 q0,q1,q2,q3;
      ldg4f(qp, q0, q1, q2, q3);                               // mutable: bypass
      float q[16], r[16];
#pragma unroll
      for (int i = 0; i < 4; ++i){
        q[i]=q0[i]; q[4+i]=q1[i]; q[8+i]=q2[i]; q[12+i]=q3[i];
        float4 rv = ld4(rp + i*4);
        r[4*i]=rv.x; r[4*i+1]=rv.y; r[4*i+2]=rv.z; r[4*i+3]=rv.w;
      }
#pragma unroll
      for (int pi = 0; pi < 8; ++pi){
        const int s = sg*8 + pi;
        const ushort* pp = pcb + (s*64 + b)*1024 + lane*16;    // read-only: cached
        uint4 v0 = *(const uint4*)pp;
        uint4 v1 = *(const uint4*)(pp + 8);
        float acc;
        acc  = tanhfast(u2f(v0.x << 16)              + q[0])  * r[0];
        acc  = fmaf(tanhfast(u2f(v0.x & 0xffff0000u) + q[1]),  r[1],  acc);
        acc  = fmaf(tanhfast(u2f(v0.y << 16)         + q[2]),  r[2],  acc);
        acc  = fmaf(tanhfast(u2f(v0.y & 0xffff0000u) + q[3]),  r[3],  acc);
        acc  = fmaf(tanhfast(u2f(v0.z << 16)         + q[4]),  r[4],  acc);
        acc  = fmaf(tanhfast(u2f(v0.z & 0xffff0000u) + q[5]),  r[5],  acc);
        acc  = fmaf(tanhfast(u2f(v0.w << 16)         + q[6]),  r[6],  acc);
        acc  = fmaf(tanhfast(u2f(v0.w & 0xffff0000u) + q[7]),  r[7],  acc);
        acc  = fmaf(tanhfast(u2f(v1.x << 16)         + q[8]),  r[8],  acc);
        acc  = fmaf(tanhfast(u2f(v1.x & 0xffff0000u) + q[9]),  r[9],  acc);
        acc  = fmaf(tanhfast(u2f(v1.y << 16)         + q[10]), r[10], acc);
        acc  = fmaf(tanhfast(u2f(v1.y & 0xffff0000u) + q[11]), r[11], acc);
        acc  = fmaf(tanhfast(u2f(v1.z << 16)         + q[12]), r[12], acc);
        acc  = fmaf(tanhfast(u2f(v1.z & 0xffff0000u) + q[13]), r[13], acc);
        acc  = fmaf(tanhfast(u2f(v1.w << 16)         + q[14]), r[14], acc);
        acc  = fmaf(tanhfast(u2f(v1.w & 0xffff0000u) + q[15]), r[15], acc);
#pragma unroll
        for (int off = 32; off; off >>= 1) acc += __shfl_xor(acc, off);
        if (lane == 0) stg_f32(logits + b*256 + s, acc);
      }
    }
    ++bu; gbar(barcnt, bu*NB);

    // ---------- Phase D: softmax + weighted ctx (block = (b, 256-c slice)) ----------
    {
      const int b = bid >> 2, cq = bid & 3;
      if (tid < 256){
        float l = ldg1f(logits + b*256 + tid);                 // mutable: bypass
        red[tid] = l; al[tid] = l;
      }
      __syncthreads();
      for (int s = 128; s; s >>= 1){ if (tid < s) red[tid] = fmaxf(red[tid], red[tid+s]); __syncthreads(); }
      float mx = red[0]; __syncthreads();
      if (tid < 256){ float e = __expf(al[tid] - mx); al[tid] = e; red[tid] = e; }
      __syncthreads();
      for (int s = 128; s; s >>= 1){ if (tid < s) red[tid] += red[tid+s]; __syncthreads(); }
      float inv = rcpf_(red[0]);
      const int ci = tid & 63, sh = tid >> 6;
      const int c = cq*256 + ci*4;
      const ushort* cp = ctxb + (b*256 + sh*32)*1024 + c;      // read-only: cached
      float a0=0.f, a1=0.f, a2=0.f, a3=0.f;
#pragma unroll 8
      for (int s = 0; s < 32; ++s){
        ushort4 v = *(const ushort4*)(cp + s*1024);
        float aw = al[sh*32 + s];
        a0 = fmaf(aw, bf2f(v.x), a0);
        a1 = fmaf(aw, bf2f(v.y), a1);
        a2 = fmaf(aw, bf2f(v.z), a2);
        a3 = fmaf(aw, bf2f(v.w), a3);
      }
      part4[sh][ci] = make_float4(a0, a1, a2, a3);
      __syncthreads();
      if (tid < 256){
        const float* pf = (const float*)part4;
        float s0 = 0.f;
#pragma unroll
        for (int s2 = 0; s2 < 8; ++s2) s0 += pf[s2*256 + tid];
        stg_u16(wctxbf + b*1024 + cq*256 + tid, (unsigned)f2bf(s0 * inv));
      }
    }
    ++bu; gbar(barcnt, bu*NB);

    // ---------- Phase E: gates2 (4 gates x 4 h-cols) + LSTM2 ----------
    {
      const int g = cc >> 2;
      const int ncol = (g << 10) + (bid << 2) + (cc & 3);
      const int arow = strip*16 + cc;
      const ushort* wp = w3b + ncol*1024 + kh*512 + ko;
      const ushort* ap = wctxbf + arow*1024 + kh*512 + ko;
      f32x4 a = {0.f,0.f,0.f,0.f};
      V8 b0 = ldg8(ap);
      a = MFMA(b0.v0, *(const short8v*)(wp + 0*32), a);
      a = MFMA(b0.v1, *(const short8v*)(wp + 1*32), a);
      a = MFMA(b0.v2, *(const short8v*)(wp + 2*32), a);
      a = MFMA(b0.v3, *(const short8v*)(wp + 3*32), a);
      a = MFMA(b0.v4, *(const short8v*)(wp + 4*32), a);
      a = MFMA(b0.v5, *(const short8v*)(wp + 5*32), a);
      a = MFMA(b0.v6, *(const short8v*)(wp + 6*32), a);
      a = MFMA(b0.v7, *(const short8v*)(wp + 7*32), a);
      V8 b1 = ldg8(ap + 256);
      a = MFMA(b1.v0, *(const short8v*)(wp + 8*32), a);
      a = MFMA(b1.v1, *(const short8v*)(wp + 9*32), a);
      a = MFMA(b1.v2, *(const short8v*)(wp + 10*32), a);
      a = MFMA(b1.v3, *(const short8v*)(wp + 11*32), a);
      a = MFMA(b1.v4, *(const short8v*)(wp + 12*32), a);
      a = MFMA(b1.v5, *(const short8v*)(wp + 13*32), a);
      a = MFMA(b1.v6, *(const short8v*)(wp + 14*32), a);
      a = MFMA(b1.v7, *(const short8v*)(wp + 15*32), a);
      const int rb = strip*16 + ((lane >> 4) << 2);
#pragma unroll
      for (int r = 0; r < 4; ++r) lred[kh][rb + r][cc] = a[r];
    }
    __syncthreads();
    if (tid < 256){
      const int row = tid >> 2, hi = tid & 3, hh = (bid << 2) + hi;
      const float* gp = hyp + row*5120 + 1024 + hh;
      float ga, gb, gc, gd;
      ldg4s(gp, gp+1024, gp+2048, gp+3072, ga, gb, gc, gd);    // mutable: bypass
      float gi = lred[0][row][hi]      + lred[1][row][hi]      + ga + b2s[hh];
      float gf = lred[0][row][4+hi]    + lred[1][row][4+hi]    + gb + b2s[1024+hh];
      float gg = lred[0][row][8+hi]    + lred[1][row][8+hi]    + gc + b2s[2048+hh];
      float go = lred[0][row][12+hi]   + lred[1][row][12+hi]   + gd + b2s[3072+hh];
      float c2 = sigf(gf)*cym[row*1024+hh] + sigf(gi)*tanhfast(gg);
      float hv = sigf(go)*tanhfast(c2);
      out[t*65536 + row*1024 + hh] = hv;
      cxb[row*1024+hh] = c2;
      hxb[row*1024+hh] = hv;
      stg_u16(hxbbf + row*1024 + hh, (unsigned)f2bf(hv));
    }
    ++bu; gbar(barcnt, bu*NB);
  }
}

extern "C" void kernel_launch(void* const* d_in, const int* in_sizes, int n_in,
                              void* d_out, int out_size, void* d_ws, size_t ws_size,
                              hipStream_t stream) {
  const float* input = (const float*)d_in[0];
  const float* hx    = (const float*)d_in[1];
  const float* cx    = (const float*)d_in[2];
  const float* ctxp  = (const float*)d_in[3];
  const float* iw1   = (const float*)d_in[4];
  const float* hw1   = (const float*)d_in[5];
  const float* ib1   = (const float*)d_in[6];
  const float* hb1   = (const float*)d_in[7];
  const float* iw2   = (const float*)d_in[8];
  const float* hw2   = (const float*)d_in[9];
  const float* ib2   = (const float*)d_in[10];
  const float* hb2   = (const float*)d_in[11];
  const float* c2a   = (const float*)d_in[12];
  const float* b_c2a = (const float*)d_in[13];
  const float* h2a   = (const float*)d_in[14];
  const float* i2a   = (const float*)d_in[15];
  const float* r2a   = (const float*)d_in[16];
  float* out = (float*)d_out;

  char* base = (char*)d_ws;
  ushort* pcb    = (ushort*)(base);                     // 33,554,432
  ushort* ctxb   = (ushort*)(base + 33554432);          // 33,554,432
  ushort* xb     = (ushort*)(base + 67108864);          // 16,777,216
  ushort* w1b    = (ushort*)(base + 83886080);          // 12,582,912
  ushort* w2b    = (ushort*)(base + 96468992);          // 10,485,760
  ushort* w3b    = (ushort*)(base + 106954752);         //  8,388,608
  ushort* i2aT   = (ushort*)(base + 115343360);         //  1,048,576
  float*  hyp    = (float*)(base + 116391936);          //  1,310,720
  float*  cym    = (float*)(base + 117702656);          //    262,144
  float*  hxb    = (float*)(base + 117964800);          //    262,144
  float*  cxb    = (float*)(base + 118226944);          //    262,144
  ushort* hybf   = (ushort*)(base + 118489088);         //    131,072
  ushort* hxbbf  = (ushort*)(base + 118620160);         //    131,072
  ushort* wctxbf = (ushort*)(base + 118751232);         //    131,072
  float*  logits = (float*)(base + 118882304);          //     65,536
  float*  b1s    = (float*)(base + 118947840);          //     16,384
  float*  b2s    = (float*)(base + 118964224);          //     16,384
  unsigned* barcnt = (unsigned*)(base + 118980608);     //        256

  hipMemsetAsync(barcnt, 0, 256, stream);
  hipMemcpyAsync(hxb, hx, 262144, hipMemcpyDeviceToDevice, stream);
  hipMemcpyAsync(cxb, cx, 262144, hipMemcpyDeviceToDevice, stream);

  k_cvthx<<<64,   256, 0, stream>>>(hx, hxbbf);
  k_bias<<<16,    256, 0, stream>>>(ib1, hb1, ib2, hb2, b1s, b2s);
  k_w1  <<<6144,  256, 0, stream>>>(iw1, hw1, w1b);
  k_w2  <<<5120,  256, 0, stream>>>(h2a, hw2, w2b);
  k_w3  <<<4096,  256, 0, stream>>>(iw2, w3b);
  k_ctxT<<<16384, 256, 0, stream>>>(ctxp, ctxb);
  k_xb  <<<8192,  256, 0, stream>>>(input, xb);
  k_i2aT<<<2048,  256, 0, stream>>>(i2a, i2aT);
  k_pc  <<<dim3(256,16), 256, 0, stream>>>(ctxp, c2a, b_c2a, pcb);

  k_fused<<<NB, 512, 0, stream>>>(xb, w1b, w2b, w3b, i2aT, pcb, ctxb, r2a,
                                  b1s, b2s, hyp, cym, cxb, hxb, hybf, hxbbf,
                                  wctxbf, logits, out, barcnt);

  hipMemcpyAsync(out + 16777216,         hxb, 262144, hipMemcpyDeviceToDevice, stream);
  hipMemcpyAsync(out + 16777216 + 65536, cxb, 262144, hipMemcpyDeviceToDevice, stream);
}

// Round 9
// 24669.456 us; speedup vs baseline: 2.1491x; 1.0393x over previous
//
#include <hip/hip_runtime.h>

typedef __attribute__((ext_vector_type(8))) short short8v;
typedef __attribute__((ext_vector_type(4))) float f32x4;

#define MFMA(a,b,c) __builtin_amdgcn_mfma_f32_16x16x32_bf16((a),(b),(c),0,0,0)
#define NB 256

__device__ __forceinline__ float rcpf_(float x){ return __builtin_amdgcn_rcpf(x); }
__device__ __forceinline__ float sigf(float x){ return rcpf_(1.0f + __expf(-x)); }
__device__ __forceinline__ float tanhfast(float x){ return fmaf(-2.0f, rcpf_(1.0f + __expf(2.0f*x)), 1.0f); }
__device__ __forceinline__ float bf2f(unsigned short u){ union{unsigned int i; float f;} v; v.i = ((unsigned int)u)<<16; return v.f; }
__device__ __forceinline__ float u2f(unsigned int i){ union{unsigned int i; float f;} v; v.i = i; return v.f; }
__device__ __forceinline__ unsigned short f2bf(float f){ union{float f; unsigned int i;} v; v.f=f; unsigned int x = v.i + 0x7fffu + ((v.i>>16)&1u); return (unsigned short)(x>>16); }
__device__ __forceinline__ float4 ld4(const float* p){ return *(const float4*)p; }

// write-through stores: value lands at the coherence point; no dirty L2 lines exist.
__device__ __forceinline__ void stg_f32(float* p, float v){
  asm volatile("global_store_dword %0, %1, off sc0 sc1" :: "v"(p), "v"(v) : "memory");
}
__device__ __forceinline__ void stg_u16(ushort* p, unsigned v){
  asm volatile("global_store_short %0, %1, off sc0 sc1" :: "v"(p), "v"(v) : "memory");
}

// grid barrier: RELAXED spin (no invalidate per poll) + ONE acquire after success.
// The single acquire invalidates L1/L2 once per barrier -> readers refetch fresh
// data through the normal cache path and get L2-amortized broadcast.
__device__ __forceinline__ void gbar(unsigned* cnt, unsigned target){
  asm volatile("s_waitcnt vmcnt(0) lgkmcnt(0)" ::: "memory");
  __syncthreads();
  if (threadIdx.x == 0){
    __hip_atomic_fetch_add(cnt, 1u, __ATOMIC_RELAXED, __HIP_MEMORY_SCOPE_AGENT);
    while (__hip_atomic_load(cnt, __ATOMIC_RELAXED, __HIP_MEMORY_SCOPE_AGENT) < target)
      __builtin_amdgcn_s_sleep(4);
    (void)__hip_atomic_load(cnt, __ATOMIC_ACQUIRE, __HIP_MEMORY_SCOPE_AGENT);
  }
  __syncthreads();
}

// ============ prep kernels (proven) ============
__global__ __launch_bounds__(256) void k_w1(const float* __restrict__ iw1, const float* __restrict__ hw1,
                                            ushort* __restrict__ w1b){
  int idx4 = (blockIdx.x*256 + threadIdx.x) * 4;
  int n = idx4 / 1536, k = idx4 % 1536;
  float4 v = (k < 512) ? *(const float4*)(iw1 + n*512 + k)
                       : *(const float4*)(hw1 + n*1024 + (k - 512));
  ushort4 o; o.x=f2bf(v.x); o.y=f2bf(v.y); o.z=f2bf(v.z); o.w=f2bf(v.w);
  *(ushort4*)(w1b + idx4) = o;
}
__global__ __launch_bounds__(256) void k_w2(const float* __restrict__ h2a, const float* __restrict__ hw2,
                                            ushort* __restrict__ w2b){
  int idx4 = (blockIdx.x*256 + threadIdx.x) * 4;
  int n = idx4 >> 10, k = idx4 & 1023;
  float4 v = (n < 1024) ? *(const float4*)(h2a + n*1024 + k)
                        : *(const float4*)(hw2 + (n-1024)*1024 + k);
  ushort4 o; o.x=f2bf(v.x); o.y=f2bf(v.y); o.z=f2bf(v.z); o.w=f2bf(v.w);
  *(ushort4*)(w2b + idx4) = o;
}
__global__ __launch_bounds__(256) void k_w3(const float* __restrict__ iw2, ushort* __restrict__ w3b){
  int idx4 = (blockIdx.x*256 + threadIdx.x) * 4;
  float4 v = *(const float4*)(iw2 + idx4);
  ushort4 o; o.x=f2bf(v.x); o.y=f2bf(v.y); o.z=f2bf(v.z); o.w=f2bf(v.w);
  *(ushort4*)(w3b + idx4) = o;
}
__global__ __launch_bounds__(256) void k_ctxT(const float* __restrict__ ctx, ushort* __restrict__ ctxb){
  int idx4 = (blockIdx.x*256 + threadIdx.x) * 4;
  int c = idx4 & 1023, s = (idx4 >> 10) & 255, b = idx4 >> 18;
  float4 v = *(const float4*)(ctx + (s*64 + b)*1024 + c);
  ushort4 o; o.x=f2bf(v.x); o.y=f2bf(v.y); o.z=f2bf(v.z); o.w=f2bf(v.w);
  *(ushort4*)(ctxb + idx4) = o;
}
__global__ __launch_bounds__(256) void k_xb(const float* __restrict__ inp, ushort* __restrict__ xb){
  int idx4 = (blockIdx.x*256 + threadIdx.x) * 4;
  int k = idx4 & 511, b = (idx4 >> 9) & 63, t = idx4 >> 15;
  float4 v = *(const float4*)(inp + (b*256 + t)*512 + k);
  ushort4 o; o.x=f2bf(v.x); o.y=f2bf(v.y); o.z=f2bf(v.z); o.w=f2bf(v.w);
  *(ushort4*)(xb + idx4) = o;
}
__global__ __launch_bounds__(256) void k_i2aT(const float* __restrict__ i2a, ushort* __restrict__ i2aT){
  int idx = blockIdx.x*256 + threadIdx.x;
  int n = idx & 1023, k = idx >> 10;
  i2aT[n*512 + k] = f2bf(i2a[k*1024 + n]);
}
__global__ __launch_bounds__(256) void k_cvthx(const float* __restrict__ hx, ushort* __restrict__ hxbbf){
  int i4 = (blockIdx.x*256 + threadIdx.x)*4;
  float4 v = ld4(hx + i4);
  ushort4 o; o.x=f2bf(v.x); o.y=f2bf(v.y); o.z=f2bf(v.z); o.w=f2bf(v.w);
  *(ushort4*)(hxbbf + i4) = o;
}
__global__ __launch_bounds__(256) void k_bias(const float* __restrict__ ib1, const float* __restrict__ hb1,
                                              const float* __restrict__ ib2, const float* __restrict__ hb2,
                                              float* __restrict__ b1s, float* __restrict__ b2s){
  int i = blockIdx.x*256 + threadIdx.x;
  b1s[i] = ib1[i] + hb1[i];
  b2s[i] = ib2[i] + hb2[i];
}

__global__ __launch_bounds__(256) void k_pc(const float* __restrict__ ctxp, const float* __restrict__ c2a,
                                            const float* __restrict__ bc, ushort* __restrict__ pcb){
  __shared__ __align__(16) float As[32][68];
  __shared__ __align__(16) float Bs[32][68];
  const int tid = threadIdx.x;
  const int m0 = blockIdx.x * 64;
  const int n0 = blockIdx.y * 64;
  const int tx = tid & 15, ty = tid >> 4;
  float acc[4][4] = {};
  for (int k0 = 0; k0 < 1024; k0 += 32){
#pragma unroll
    for (int l = 0; l < 8; ++l){
      int idx = l*256 + tid; int m = idx >> 5, k = idx & 31;
      As[k][m] = ctxp[(m0+m)*1024 + k0 + k];
    }
#pragma unroll
    for (int l = 0; l < 8; ++l){
      int idx = l*256 + tid; int k = idx >> 6, n = idx & 63;
      Bs[k][n] = c2a[(k0+k)*1024 + n0 + n];
    }
    __syncthreads();
#pragma unroll
    for (int k = 0; k < 32; ++k){
      float4 a4 = *(const float4*)&As[k][4*ty];
      float4 b4 = *(const float4*)&Bs[k][4*tx];
      float av[4] = {a4.x, a4.y, a4.z, a4.w};
      float bv[4] = {b4.x, b4.y, b4.z, b4.w};
#pragma unroll
      for (int i = 0; i < 4; ++i)
#pragma unroll
        for (int j = 0; j < 4; ++j) acc[i][j] = fmaf(av[i], bv[j], acc[i][j]);
    }
    __syncthreads();
  }
#pragma unroll
  for (int i = 0; i < 4; ++i){
    int m = m0 + 4*ty + i;
    int n = n0 + 4*tx;
    ushort4 o;
    o.x = f2bf(acc[i][0] + bc[n]);
    o.y = f2bf(acc[i][1] + bc[n+1]);
    o.z = f2bf(acc[i][2] + bc[n+2]);
    o.w = f2bf(acc[i][3] + bc[n+3]);
    *(ushort4*)(pcb + m*1024 + n) = o;
  }
}

// ============ THE persistent scan kernel: 256 blocks x 512 thr ============
__global__ __launch_bounds__(512, 1) void k_fused(
    const ushort* __restrict__ xb, const ushort* __restrict__ w1b,
    const ushort* __restrict__ w2b, const ushort* __restrict__ w3b,
    const ushort* __restrict__ i2aT, const ushort* __restrict__ pcb,
    const ushort* __restrict__ ctxb, const float* __restrict__ r2a,
    const float* __restrict__ b1s, const float* __restrict__ b2s,
    float* __restrict__ hyp, float* __restrict__ cym,
    float* __restrict__ cxb, float* __restrict__ hxb,
    ushort* __restrict__ hybf, ushort* __restrict__ hxbbf,
    ushort* __restrict__ wctxbf, float* __restrict__ logits,
    float* __restrict__ out, unsigned* __restrict__ barcnt)
{
  __shared__ float lred[2][64][17];
  __shared__ float al[256];
  __shared__ float red[256];
  __shared__ float4 part4[8][64];
  const int tid = threadIdx.x;
  const int bid = blockIdx.x;
  const int lane = tid & 63;
  const int w = tid >> 6;
  const int strip = w & 3;
  const int kh = w >> 2;
  const int ko = (lane >> 4) << 3;
  const int cc = lane & 15;
  unsigned bu = 0;

  for (int t = 0; t < 256; ++t){
    // ---------- Phase A: gates1 (4 gates x 4 h-cols per block) + LSTM1 ----------
    {
      const int g = cc >> 2;
      const int ncol = (g << 10) + (bid << 2) + (cc & 3);
      const int arow = strip*16 + cc;
      const ushort* wp = w1b + ncol*1536 + kh*768 + ko;
      f32x4 a = {0.f,0.f,0.f,0.f};
      if (kh == 0){
        const ushort* xp = xb + (t*64 + arow)*512 + ko;
#pragma unroll
        for (int it = 0; it < 16; ++it)
          a = MFMA(*(const short8v*)(xp + it*32), *(const short8v*)(wp + it*32), a);
        const ushort* hp = hxbbf + arow*1024 + ko;
#pragma unroll
        for (int it = 0; it < 8; ++it)
          a = MFMA(*(const short8v*)(hp + it*32), *(const short8v*)(wp + (16+it)*32), a);
      } else {
        const ushort* hp = hxbbf + arow*1024 + 256 + ko;
#pragma unroll
        for (int it = 0; it < 24; ++it)
          a = MFMA(*(const short8v*)(hp + it*32), *(const short8v*)(wp + it*32), a);
      }
      const int rb = strip*16 + ((lane >> 4) << 2);
#pragma unroll
      for (int r = 0; r < 4; ++r) lred[kh][rb + r][cc] = a[r];
    }
    __syncthreads();
    if (tid < 256){
      const int row = tid >> 2, hi = tid & 3, hh = (bid << 2) + hi;
      float gi = lred[0][row][hi]      + lred[1][row][hi]      + b1s[hh];
      float gf = lred[0][row][4+hi]    + lred[1][row][4+hi]    + b1s[1024+hh];
      float gg = lred[0][row][8+hi]    + lred[1][row][8+hi]    + b1s[2048+hh];
      float go = lred[0][row][12+hi]   + lred[1][row][12+hi]   + b1s[3072+hh];
      float c1 = sigf(gf)*cxb[row*1024+hh] + sigf(gi)*tanhfast(gg);
      stg_f32(cym + row*1024 + hh, c1);
      stg_u16(hybf + row*1024 + hh, (unsigned)f2bf(sigf(go)*tanhfast(c1)));
    }
    ++bu; gbar(barcnt, bu*NB);

    // ---------- Phase B: hyproj (N=5120, 320 tiles of 16) + i2a fold ----------
    // tile bid for everyone; tiles 256..319 go to blocks 64..127 (blocks 0..63 carry the fold)
    {
      const int t2 = (bid >= 64 && bid < 128) ? bid + 192 : -1;
#pragma unroll 1
      for (int p = 0; p < 2; ++p){
        const int tt = p ? t2 : bid;
        if (tt >= 0){
          const int ncol = tt*16 + cc;
          const int arow = strip*16 + cc;
          const ushort* wp = w2b + ncol*1024 + kh*512 + ko;
          const ushort* hp = hybf + arow*1024 + kh*512 + ko;
          f32x4 a = {0.f,0.f,0.f,0.f};
#pragma unroll
          for (int it = 0; it < 16; ++it)
            a = MFMA(*(const short8v*)(hp + it*32), *(const short8v*)(wp + it*32), a);
          if (tt < 64){
            const ushort* ip = i2aT + ncol*512 + kh*256 + ko;
            const ushort* xp = xb + (t*64 + arow)*512 + kh*256 + ko;
#pragma unroll
            for (int it = 0; it < 8; ++it)
              a = MFMA(*(const short8v*)(xp + it*32), *(const short8v*)(ip + it*32), a);
          }
          const int rb = strip*16 + ((lane >> 4) << 2);
#pragma unroll
          for (int r = 0; r < 4; ++r) lred[kh][rb + r][cc] = a[r];
          __syncthreads();
          for (int e = tid; e < 1024; e += 512){
            int row = e >> 4, c2 = e & 15;
            stg_f32(hyp + row*5120 + tt*16 + c2, lred[0][row][c2] + lred[1][row][c2]);
          }
          __syncthreads();
        }
      }
    }
    ++bu; gbar(barcnt, bu*NB);

    // ---------- Phase C: logits (2048 waves, 8 s each) ----------
    {
      const int b = bid >> 2;
      const int sg = ((bid & 3) << 3) + w;
      const float* qp = hyp + b*5120 + lane*16;
      const float* rp = r2a + lane*16;
      float q[16], r[16];
#pragma unroll
      for (int i = 0; i < 4; ++i){
        float4 qv = ld4(qp + i*4);
        float4 rv = ld4(rp + i*4);
        q[4*i]=qv.x; q[4*i+1]=qv.y; q[4*i+2]=qv.z; q[4*i+3]=qv.w;
        r[4*i]=rv.x; r[4*i+1]=rv.y; r[4*i+2]=rv.z; r[4*i+3]=rv.w;
      }
#pragma unroll
      for (int pi = 0; pi < 8; ++pi){
        const int s = sg*8 + pi;
        const ushort* pp = pcb + (s*64 + b)*1024 + lane*16;
        uint4 v0 = *(const uint4*)pp;
        uint4 v1 = *(const uint4*)(pp + 8);
        float acc;
        acc  = tanhfast(u2f(v0.x << 16)              + q[0])  * r[0];
        acc  = fmaf(tanhfast(u2f(v0.x & 0xffff0000u) + q[1]),  r[1],  acc);
        acc  = fmaf(tanhfast(u2f(v0.y << 16)         + q[2]),  r[2],  acc);
        acc  = fmaf(tanhfast(u2f(v0.y & 0xffff0000u) + q[3]),  r[3],  acc);
        acc  = fmaf(tanhfast(u2f(v0.z << 16)         + q[4]),  r[4],  acc);
        acc  = fmaf(tanhfast(u2f(v0.z & 0xffff0000u) + q[5]),  r[5],  acc);
        acc  = fmaf(tanhfast(u2f(v0.w << 16)         + q[6]),  r[6],  acc);
        acc  = fmaf(tanhfast(u2f(v0.w & 0xffff0000u) + q[7]),  r[7],  acc);
        acc  = fmaf(tanhfast(u2f(v1.x << 16)         + q[8]),  r[8],  acc);
        acc  = fmaf(tanhfast(u2f(v1.x & 0xffff0000u) + q[9]),  r[9],  acc);
        acc  = fmaf(tanhfast(u2f(v1.y << 16)         + q[10]), r[10], acc);
        acc  = fmaf(tanhfast(u2f(v1.y & 0xffff0000u) + q[11]), r[11], acc);
        acc  = fmaf(tanhfast(u2f(v1.z << 16)         + q[12]), r[12], acc);
        acc  = fmaf(tanhfast(u2f(v1.z & 0xffff0000u) + q[13]), r[13], acc);
        acc  = fmaf(tanhfast(u2f(v1.w << 16)         + q[14]), r[14], acc);
        acc  = fmaf(tanhfast(u2f(v1.w & 0xffff0000u) + q[15]), r[15], acc);
#pragma unroll
        for (int off = 32; off; off >>= 1) acc += __shfl_xor(acc, off);
        if (lane == 0) stg_f32(logits + b*256 + s, acc);
      }
    }
    ++bu; gbar(barcnt, bu*NB);

    // ---------- Phase D: softmax + weighted ctx (block = (b, 256-c slice)) ----------
    {
      const int b = bid >> 2, cq = bid & 3;
      if (tid < 256){ float l = logits[b*256 + tid]; red[tid] = l; al[tid] = l; }
      __syncthreads();
      for (int s = 128; s; s >>= 1){ if (tid < s) red[tid] = fmaxf(red[tid], red[tid+s]); __syncthreads(); }
      float mx = red[0]; __syncthreads();
      if (tid < 256){ float e = __expf(al[tid] - mx); al[tid] = e; red[tid] = e; }
      __syncthreads();
      for (int s = 128; s; s >>= 1){ if (tid < s) red[tid] += red[tid+s]; __syncthreads(); }
      float inv = rcpf_(red[0]);
      const int ci = tid & 63, sh = tid >> 6;
      const int c = cq*256 + ci*4;
      const ushort* cp = ctxb + (b*256 + sh*32)*1024 + c;
      float a0=0.f, a1=0.f, a2=0.f, a3=0.f;
#pragma unroll 8
      for (int s = 0; s < 32; ++s){
        ushort4 v = *(const ushort4*)(cp + s*1024);
        float aw = al[sh*32 + s];
        a0 = fmaf(aw, bf2f(v.x), a0);
        a1 = fmaf(aw, bf2f(v.y), a1);
        a2 = fmaf(aw, bf2f(v.z), a2);
        a3 = fmaf(aw, bf2f(v.w), a3);
      }
      part4[sh][ci] = make_float4(a0, a1, a2, a3);
      __syncthreads();
      if (tid < 256){
        const float* pf = (const float*)part4;
        float s0 = 0.f;
#pragma unroll
        for (int s2 = 0; s2 < 8; ++s2) s0 += pf[s2*256 + tid];
        stg_u16(wctxbf + b*1024 + cq*256 + tid, (unsigned)f2bf(s0 * inv));
      }
    }
    ++bu; gbar(barcnt, bu*NB);

    // ---------- Phase E: gates2 (4 gates x 4 h-cols) + LSTM2 ----------
    {
      const int g = cc >> 2;
      const int ncol = (g << 10) + (bid << 2) + (cc & 3);
      const int arow = strip*16 + cc;
      const ushort* wp = w3b + ncol*1024 + kh*512 + ko;
      const ushort* ap = wctxbf + arow*1024 + kh*512 + ko;
      f32x4 a = {0.f,0.f,0.f,0.f};
#pragma unroll
      for (int it = 0; it < 16; ++it)
        a = MFMA(*(const short8v*)(ap + it*32), *(const short8v*)(wp + it*32), a);
      const int rb = strip*16 + ((lane >> 4) << 2);
#pragma unroll
      for (int r = 0; r < 4; ++r) lred[kh][rb + r][cc] = a[r];
    }
    __syncthreads();
    if (tid < 256){
      const int row = tid >> 2, hi = tid & 3, hh = (bid << 2) + hi;
      const float* gp = hyp + row*5120 + 1024 + hh;
      float ga = gp[0], gb = gp[1024], gc = gp[2048], gd = gp[3072];
      float gi = lred[0][row][hi]      + lred[1][row][hi]      + ga + b2s[hh];
      float gf = lred[0][row][4+hi]    + lred[1][row][4+hi]    + gb + b2s[1024+hh];
      float gg = lred[0][row][8+hi]    + lred[1][row][8+hi]    + gc + b2s[2048+hh];
      float go = lred[0][row][12+hi]   + lred[1][row][12+hi]   + gd + b2s[3072+hh];
      float c2 = sigf(gf)*cym[row*1024+hh] + sigf(gi)*tanhfast(gg);
      float hv = sigf(go)*tanhfast(c2);
      stg_f32(out + t*65536 + row*1024 + hh, hv);
      stg_f32(cxb + row*1024 + hh, c2);
      stg_f32(hxb + row*1024 + hh, hv);
      stg_u16(hxbbf + row*1024 + hh, (unsigned)f2bf(hv));
    }
    ++bu; gbar(barcnt, bu*NB);
  }
}

extern "C" void kernel_launch(void* const* d_in, const int* in_sizes, int n_in,
                              void* d_out, int out_size, void* d_ws, size_t ws_size,
                              hipStream_t stream) {
  const float* input = (const float*)d_in[0];
  const float* hx    = (const float*)d_in[1];
  const float* cx    = (const float*)d_in[2];
  const float* ctxp  = (const float*)d_in[3];
  const float* iw1   = (const float*)d_in[4];
  const float* hw1   = (const float*)d_in[5];
  const float* ib1   = (const float*)d_in[6];
  const float* hb1   = (const float*)d_in[7];
  const float* iw2   = (const float*)d_in[8];
  const float* hw2   = (const float*)d_in[9];
  const float* ib2   = (const float*)d_in[10];
  const float* hb2   = (const float*)d_in[11];
  const float* c2a   = (const float*)d_in[12];
  const float* b_c2a = (const float*)d_in[13];
  const float* h2a   = (const float*)d_in[14];
  const float* i2a   = (const float*)d_in[15];
  const float* r2a   = (const float*)d_in[16];
  float* out = (float*)d_out;

  char* base = (char*)d_ws;
  ushort* pcb    = (ushort*)(base);                     // 33,554,432
  ushort* ctxb   = (ushort*)(base + 33554432);          // 33,554,432
  ushort* xb     = (ushort*)(base + 67108864);          // 16,777,216
  ushort* w1b    = (ushort*)(base + 83886080);          // 12,582,912
  ushort* w2b    = (ushort*)(base + 96468992);          // 10,485,760
  ushort* w3b    = (ushort*)(base + 106954752);         //  8,388,608
  ushort* i2aT   = (ushort*)(base + 115343360);         //  1,048,576
  float*  hyp    = (float*)(base + 116391936);          //  1,310,720
  float*  cym    = (float*)(base + 117702656);          //    262,144
  float*  hxb    = (float*)(base + 117964800);          //    262,144
  float*  cxb    = (float*)(base + 118226944);          //    262,144
  ushort* hybf   = (ushort*)(base + 118489088);         //    131,072
  ushort* hxbbf  = (ushort*)(base + 118620160);         //    131,072
  ushort* wctxbf = (ushort*)(base + 118751232);         //    131,072
  float*  logits = (float*)(base + 118882304);          //     65,536
  float*  b1s    = (float*)(base + 118947840);          //     16,384
  float*  b2s    = (float*)(base + 118964224);          //     16,384
  unsigned* barcnt = (unsigned*)(base + 118980608);     //        256

  hipMemsetAsync(barcnt, 0, 256, stream);
  hipMemcpyAsync(hxb, hx, 262144, hipMemcpyDeviceToDevice, stream);
  hipMemcpyAsync(cxb, cx, 262144, hipMemcpyDeviceToDevice, stream);

  k_cvthx<<<64,   256, 0, stream>>>(hx, hxbbf);
  k_bias<<<16,    256, 0, stream>>>(ib1, hb1, ib2, hb2, b1s, b2s);
  k_w1  <<<6144,  256, 0, stream>>>(iw1, hw1, w1b);
  k_w2  <<<5120,  256, 0, stream>>>(h2a, hw2, w2b);
  k_w3  <<<4096,  256, 0, stream>>>(iw2, w3b);
  k_ctxT<<<16384, 256, 0, stream>>>(ctxp, ctxb);
  k_xb  <<<8192,  256, 0, stream>>>(input, xb);
  k_i2aT<<<2048,  256, 0, stream>>>(i2a, i2aT);
  k_pc  <<<dim3(256,16), 256, 0, stream>>>(ctxp, c2a, b_c2a, pcb);

  k_fused<<<NB, 512, 0, stream>>>(xb, w1b, w2b, w3b, i2aT, pcb, ctxb, r2a,
                                  b1s, b2s, hyp, cym, cxb, hxb, hybf, hxbbf,
                                  wctxbf, logits, out, barcnt);

  hipMemcpyAsync(out + 16777216,         hxb, 262144, hipMemcpyDeviceToDevice, stream);
  hipMemcpyAsync(out + 16777216 + 65536, cxb, 262144, hipMemcpyDeviceToDevice, stream);
}

// Round 11
// 21801.390 us; speedup vs baseline: 2.4318x; 1.1316x over previous
//
#include <hip/hip_runtime.h>

typedef __attribute__((ext_vector_type(8))) short short8v;
typedef __attribute__((ext_vector_type(4))) float f32x4;

#define MFMA(a,b,c) __builtin_amdgcn_mfma_f32_16x16x32_bf16((a),(b),(c),0,0,0)
#define NB 256

__device__ __forceinline__ float rcpf_(float x){ return __builtin_amdgcn_rcpf(x); }
__device__ __forceinline__ float sigf(float x){ return rcpf_(1.0f + __expf(-x)); }
__device__ __forceinline__ float tanhfast(float x){ return fmaf(-2.0f, rcpf_(1.0f + __expf(2.0f*x)), 1.0f); }
__device__ __forceinline__ float bf2f(unsigned short u){ union{unsigned int i; float f;} v; v.i = ((unsigned int)u)<<16; return v.f; }
__device__ __forceinline__ float u2f(unsigned int i){ union{unsigned int i; float f;} v; v.i = i; return v.f; }
__device__ __forceinline__ unsigned short f2bf(float f){ union{float f; unsigned int i;} v; v.f=f; unsigned int x = v.i + 0x7fffu + ((v.i>>16)&1u); return (unsigned short)(x>>16); }
__device__ __forceinline__ float4 ld4(const float* p){ return *(const float4*)p; }

// ---- L2-bypass helpers (sc0 sc1): cross-block mutable state only.
struct V8 { short8v v0,v1,v2,v3,v4,v5,v6,v7; };
__device__ __forceinline__ V8 ldg8(const ushort* p){
  V8 r;
  asm volatile(
    "global_load_dwordx4 %0, %8, off sc0 sc1\n\t"
    "global_load_dwordx4 %1, %8, off offset:64 sc0 sc1\n\t"
    "global_load_dwordx4 %2, %8, off offset:128 sc0 sc1\n\t"
    "global_load_dwordx4 %3, %8, off offset:192 sc0 sc1\n\t"
    "global_load_dwordx4 %4, %8, off offset:256 sc0 sc1\n\t"
    "global_load_dwordx4 %5, %8, off offset:320 sc0 sc1\n\t"
    "global_load_dwordx4 %6, %8, off offset:384 sc0 sc1\n\t"
    "global_load_dwordx4 %7, %8, off offset:448 sc0 sc1\n\t"
    "s_waitcnt vmcnt(0)"
    : "=v"(r.v0),"=v"(r.v1),"=v"(r.v2),"=v"(r.v3),"=v"(r.v4),"=v"(r.v5),"=v"(r.v6),"=v"(r.v7)
    : "v"(p));
  return r;
}
__device__ __forceinline__ void ldg4f(const float* p, f32x4& a, f32x4& b, f32x4& c, f32x4& d){
  asm volatile(
    "global_load_dwordx4 %0, %4, off sc0 sc1\n\t"
    "global_load_dwordx4 %1, %4, off offset:16 sc0 sc1\n\t"
    "global_load_dwordx4 %2, %4, off offset:32 sc0 sc1\n\t"
    "global_load_dwordx4 %3, %4, off offset:48 sc0 sc1\n\t"
    "s_waitcnt vmcnt(0)"
    : "=v"(a),"=v"(b),"=v"(c),"=v"(d) : "v"(p));
}
__device__ __forceinline__ void ldg4s(const float* p0, const float* p1, const float* p2, const float* p3,
                                      float& a, float& b, float& c, float& d){
  asm volatile(
    "global_load_dword %0, %4, off sc0 sc1\n\t"
    "global_load_dword %1, %5, off sc0 sc1\n\t"
    "global_load_dword %2, %6, off sc0 sc1\n\t"
    "global_load_dword %3, %7, off sc0 sc1\n\t"
    "s_waitcnt vmcnt(0)"
    : "=v"(a),"=v"(b),"=v"(c),"=v"(d) : "v"(p0),"v"(p1),"v"(p2),"v"(p3));
}
__device__ __forceinline__ float ldg1f(const float* p){
  float r;
  asm volatile("global_load_dword %0, %1, off sc0 sc1\n\ts_waitcnt vmcnt(0)" : "=v"(r) : "v"(p));
  return r;
}
__device__ __forceinline__ void stg_f32(float* p, float v){
  asm volatile("global_store_dword %0, %1, off sc0 sc1" :: "v"(p), "v"(v) : "memory");
}
__device__ __forceinline__ void stg_u16(ushort* p, unsigned v){
  asm volatile("global_store_short %0, %1, off sc0 sc1" :: "v"(p), "v"(v) : "memory");
}

// grid barrier: RELAXED atomics only — no cache invalidates ever.
__device__ __forceinline__ void gbar(unsigned* cnt, unsigned target){
  asm volatile("s_waitcnt vmcnt(0) lgkmcnt(0)" ::: "memory");
  __syncthreads();
  if (threadIdx.x == 0){
    __hip_atomic_fetch_add(cnt, 1u, __ATOMIC_RELAXED, __HIP_MEMORY_SCOPE_AGENT);
    while (__hip_atomic_load(cnt, __ATOMIC_RELAXED, __HIP_MEMORY_SCOPE_AGENT) < target)
      __builtin_amdgcn_s_sleep(4);
  }
  __syncthreads();
}

// ============ prep kernels (proven) ============
__global__ __launch_bounds__(256) void k_w1(const float* __restrict__ iw1, const float* __restrict__ hw1,
                                            ushort* __restrict__ w1b){
  int idx4 = (blockIdx.x*256 + threadIdx.x) * 4;
  int n = idx4 / 1536, k = idx4 % 1536;
  float4 v = (k < 512) ? *(const float4*)(iw1 + n*512 + k)
                       : *(const float4*)(hw1 + n*1024 + (k - 512));
  ushort4 o; o.x=f2bf(v.x); o.y=f2bf(v.y); o.z=f2bf(v.z); o.w=f2bf(v.w);
  *(ushort4*)(w1b + idx4) = o;
}
__global__ __launch_bounds__(256) void k_w2(const float* __restrict__ h2a, const float* __restrict__ hw2,
                                            ushort* __restrict__ w2b){
  int idx4 = (blockIdx.x*256 + threadIdx.x) * 4;
  int n = idx4 >> 10, k = idx4 & 1023;
  float4 v = (n < 1024) ? *(const float4*)(h2a + n*1024 + k)
                        : *(const float4*)(hw2 + (n-1024)*1024 + k);
  ushort4 o; o.x=f2bf(v.x); o.y=f2bf(v.y); o.z=f2bf(v.z); o.w=f2bf(v.w);
  *(ushort4*)(w2b + idx4) = o;
}
__global__ __launch_bounds__(256) void k_w3(const float* __restrict__ iw2, ushort* __restrict__ w3b){
  int idx4 = (blockIdx.x*256 + threadIdx.x) * 4;
  float4 v = *(const float4*)(iw2 + idx4);
  ushort4 o; o.x=f2bf(v.x); o.y=f2bf(v.y); o.z=f2bf(v.z); o.w=f2bf(v.w);
  *(ushort4*)(w3b + idx4) = o;
}
__global__ __launch_bounds__(256) void k_ctxT(const float* __restrict__ ctx, ushort* __restrict__ ctxb){
  int idx4 = (blockIdx.x*256 + threadIdx.x) * 4;
  int c = idx4 & 1023, s = (idx4 >> 10) & 255, b = idx4 >> 18;
  float4 v = *(const float4*)(ctx + (s*64 + b)*1024 + c);
  ushort4 o; o.x=f2bf(v.x); o.y=f2bf(v.y); o.z=f2bf(v.z); o.w=f2bf(v.w);
  *(ushort4*)(ctxb + idx4) = o;
}
__global__ __launch_bounds__(256) void k_xb(const float* __restrict__ inp, ushort* __restrict__ xb){
  int idx4 = (blockIdx.x*256 + threadIdx.x) * 4;
  int k = idx4 & 511, b = (idx4 >> 9) & 63, t = idx4 >> 15;
  float4 v = *(const float4*)(inp + (b*256 + t)*512 + k);
  ushort4 o; o.x=f2bf(v.x); o.y=f2bf(v.y); o.z=f2bf(v.z); o.w=f2bf(v.w);
  *(ushort4*)(xb + idx4) = o;
}
__global__ __launch_bounds__(256) void k_i2aT(const float* __restrict__ i2a, ushort* __restrict__ i2aT){
  int idx = blockIdx.x*256 + threadIdx.x;
  int n = idx & 1023, k = idx >> 10;
  i2aT[n*512 + k] = f2bf(i2a[k*1024 + n]);
}
__global__ __launch_bounds__(256) void k_cvthx(const float* __restrict__ hx, ushort* __restrict__ hxbbf){
  int i4 = (blockIdx.x*256 + threadIdx.x)*4;
  float4 v = ld4(hx + i4);
  ushort4 o; o.x=f2bf(v.x); o.y=f2bf(v.y); o.z=f2bf(v.z); o.w=f2bf(v.w);
  *(ushort4*)(hxbbf + i4) = o;
}
__global__ __launch_bounds__(256) void k_bias(const float* __restrict__ ib1, const float* __restrict__ hb1,
                                              const float* __restrict__ ib2, const float* __restrict__ hb2,
                                              float* __restrict__ b1s, float* __restrict__ b2s){
  int i = blockIdx.x*256 + threadIdx.x;
  b1s[i] = ib1[i] + hb1[i];
  b2s[i] = ib2[i] + hb2[i];
}

__global__ __launch_bounds__(256) void k_pc(const float* __restrict__ ctxp, const float* __restrict__ c2a,
                                            const float* __restrict__ bc, ushort* __restrict__ pcb){
  __shared__ __align__(16) float As[32][68];
  __shared__ __align__(16) float Bs[32][68];
  const int tid = threadIdx.x;
  const int m0 = blockIdx.x * 64;
  const int n0 = blockIdx.y * 64;
  const int tx = tid & 15, ty = tid >> 4;
  float acc[4][4] = {};
  for (int k0 = 0; k0 < 1024; k0 += 32){
#pragma unroll
    for (int l = 0; l < 8; ++l){
      int idx = l*256 + tid; int m = idx >> 5, k = idx & 31;
      As[k][m] = ctxp[(m0+m)*1024 + k0 + k];
    }
#pragma unroll
    for (int l = 0; l < 8; ++l){
      int idx = l*256 + tid; int k = idx >> 6, n = idx & 63;
      Bs[k][n] = c2a[(k0+k)*1024 + n0 + n];
    }
    __syncthreads();
#pragma unroll
    for (int k = 0; k < 32; ++k){
      float4 a4 = *(const float4*)&As[k][4*ty];
      float4 b4 = *(const float4*)&Bs[k][4*tx];
      float av[4] = {a4.x, a4.y, a4.z, a4.w};
      float bv[4] = {b4.x, b4.y, b4.z, b4.w};
#pragma unroll
      for (int i = 0; i < 4; ++i)
#pragma unroll
        for (int j = 0; j < 4; ++j) acc[i][j] = fmaf(av[i], bv[j], acc[i][j]);
    }
    __syncthreads();
  }
#pragma unroll
  for (int i = 0; i < 4; ++i){
    int m = m0 + 4*ty + i;
    int n = n0 + 4*tx;
    ushort4 o;
    o.x = f2bf(acc[i][0] + bc[n]);
    o.y = f2bf(acc[i][1] + bc[n+1]);
    o.z = f2bf(acc[i][2] + bc[n+2]);
    o.w = f2bf(acc[i][3] + bc[n+3]);
    *(ushort4*)(pcb + m*1024 + n) = o;
  }
}

// ============ THE persistent scan kernel: 256 blocks x 512 thr ============
// launch_bounds(512, 2): 2 waves/EU minimum -> VGPR hard-capped at 256 -> block always fits.
__global__ __launch_bounds__(512, 2) void k_fused(
    const ushort* __restrict__ xb, const ushort* __restrict__ w1b,
    const ushort* __restrict__ w2b, const ushort* __restrict__ w3b,
    const ushort* __restrict__ i2aT, const ushort* __restrict__ pcb,
    const ushort* __restrict__ ctxb, const float* __restrict__ r2a,
    const float* __restrict__ b1s, const float* __restrict__ b2s,
    float* __restrict__ hyp, float* __restrict__ cym,
    float* __restrict__ cxb, float* __restrict__ hxb,
    ushort* __restrict__ hybf, ushort* __restrict__ hxbbf,
    ushort* __restrict__ wctxbf, float* __restrict__ logits,
    float* __restrict__ out, unsigned* __restrict__ barcnt)
{
  __shared__ float lred[2][64][17];
  __shared__ float al[256];
  __shared__ float red[256];
  __shared__ float4 part4[8][64];
  const int tid = threadIdx.x;
  const int bid = blockIdx.x;
  const int lane = tid & 63;
  const int w = tid >> 6;
  const int strip = w & 3;
  const int kh = w >> 2;
  const int ko = (lane >> 4) << 3;
  const int cc = lane & 15;
  unsigned bu = 0;

  for (int t = 0; t < 256; ++t){
    // ---------- Phase A: gates1 (4 gates x 4 h-cols per block) + LSTM1 ----------
    {
      const int g = cc >> 2;
      const int ncol = (g << 10) + (bid << 2) + (cc & 3);
      const int arow = strip*16 + cc;
      const ushort* wp = w1b + ncol*1536 + kh*768 + ko;
      f32x4 a = {0.f,0.f,0.f,0.f};
      if (kh == 0){
        const ushort* xp = xb + (t*64 + arow)*512 + ko;       // read-only: cached
#pragma unroll
        for (int it = 0; it < 16; ++it)
          a = MFMA(*(const short8v*)(xp + it*32), *(const short8v*)(wp + it*32), a);
        V8 h8 = ldg8(hxbbf + arow*1024 + ko);                 // mutable: bypass
        a = MFMA(h8.v0, *(const short8v*)(wp + 16*32), a);
        a = MFMA(h8.v1, *(const short8v*)(wp + 17*32), a);
        a = MFMA(h8.v2, *(const short8v*)(wp + 18*32), a);
        a = MFMA(h8.v3, *(const short8v*)(wp + 19*32), a);
        a = MFMA(h8.v4, *(const short8v*)(wp + 20*32), a);
        a = MFMA(h8.v5, *(const short8v*)(wp + 21*32), a);
        a = MFMA(h8.v6, *(const short8v*)(wp + 22*32), a);
        a = MFMA(h8.v7, *(const short8v*)(wp + 23*32), a);
      } else {
        const ushort* hp = hxbbf + arow*1024 + 256 + ko;
        V8 b0 = ldg8(hp);
        a = MFMA(b0.v0, *(const short8v*)(wp + 0*32), a);
        a = MFMA(b0.v1, *(const short8v*)(wp + 1*32), a);
        a = MFMA(b0.v2, *(const short8v*)(wp + 2*32), a);
        a = MFMA(b0.v3, *(const short8v*)(wp + 3*32), a);
        a = MFMA(b0.v4, *(const short8v*)(wp + 4*32), a);
        a = MFMA(b0.v5, *(const short8v*)(wp + 5*32), a);
        a = MFMA(b0.v6, *(const short8v*)(wp + 6*32), a);
        a = MFMA(b0.v7, *(const short8v*)(wp + 7*32), a);
        V8 b1 = ldg8(hp + 256);
        a = MFMA(b1.v0, *(const short8v*)(wp + 8*32), a);
        a = MFMA(b1.v1, *(const short8v*)(wp + 9*32), a);
        a = MFMA(b1.v2, *(const short8v*)(wp + 10*32), a);
        a = MFMA(b1.v3, *(const short8v*)(wp + 11*32), a);
        a = MFMA(b1.v4, *(const short8v*)(wp + 12*32), a);
        a = MFMA(b1.v5, *(const short8v*)(wp + 13*32), a);
        a = MFMA(b1.v6, *(const short8v*)(wp + 14*32), a);
        a = MFMA(b1.v7, *(const short8v*)(wp + 15*32), a);
        V8 b2 = ldg8(hp + 512);
        a = MFMA(b2.v0, *(const short8v*)(wp + 16*32), a);
        a = MFMA(b2.v1, *(const short8v*)(wp + 17*32), a);
        a = MFMA(b2.v2, *(const short8v*)(wp + 18*32), a);
        a = MFMA(b2.v3, *(const short8v*)(wp + 19*32), a);
        a = MFMA(b2.v4, *(const short8v*)(wp + 20*32), a);
        a = MFMA(b2.v5, *(const short8v*)(wp + 21*32), a);
        a = MFMA(b2.v6, *(const short8v*)(wp + 22*32), a);
        a = MFMA(b2.v7, *(const short8v*)(wp + 23*32), a);
      }
      const int rb = strip*16 + ((lane >> 4) << 2);
#pragma unroll
      for (int r = 0; r < 4; ++r) lred[kh][rb + r][cc] = a[r];
    }
    __syncthreads();
    if (tid < 256){
      const int row = tid >> 2, hi = tid & 3, hh = (bid << 2) + hi;
      float gi = lred[0][row][hi]      + lred[1][row][hi]      + b1s[hh];
      float gf = lred[0][row][4+hi]    + lred[1][row][4+hi]    + b1s[1024+hh];
      float gg = lred[0][row][8+hi]    + lred[1][row][8+hi]    + b1s[2048+hh];
      float go = lred[0][row][12+hi]   + lred[1][row][12+hi]   + b1s[3072+hh];
      float c1 = sigf(gf)*cxb[row*1024+hh] + sigf(gi)*tanhfast(gg);   // block-local: cached
      cym[row*1024+hh] = c1;
      stg_u16(hybf + row*1024 + hh, (unsigned)f2bf(sigf(go)*tanhfast(c1)));
    }
    ++bu; gbar(barcnt, bu*NB);

    // ---------- Phase B: hyproj (N=5120, 320 tiles of 16) + i2a fold ----------
    {
      const int t2 = (bid >= 64 && bid < 128) ? bid + 192 : -1;
#pragma unroll 1
      for (int p = 0; p < 2; ++p){
        const int tt = p ? t2 : bid;
        if (tt >= 0){
          const int ncol = tt*16 + cc;
          const int arow = strip*16 + cc;
          const ushort* wp = w2b + ncol*1024 + kh*512 + ko;
          const ushort* hp = hybf + arow*1024 + kh*512 + ko;
          f32x4 a = {0.f,0.f,0.f,0.f};
          V8 b0 = ldg8(hp);                                   // mutable: bypass
          a = MFMA(b0.v0, *(const short8v*)(wp + 0*32), a);
          a = MFMA(b0.v1, *(const short8v*)(wp + 1*32), a);
          a = MFMA(b0.v2, *(const short8v*)(wp + 2*32), a);
          a = MFMA(b0.v3, *(const short8v*)(wp + 3*32), a);
          a = MFMA(b0.v4, *(const short8v*)(wp + 4*32), a);
          a = MFMA(b0.v5, *(const short8v*)(wp + 5*32), a);
          a = MFMA(b0.v6, *(const short8v*)(wp + 6*32), a);
          a = MFMA(b0.v7, *(const short8v*)(wp + 7*32), a);
          V8 b1 = ldg8(hp + 256);
          a = MFMA(b1.v0, *(const short8v*)(wp + 8*32), a);
          a = MFMA(b1.v1, *(const short8v*)(wp + 9*32), a);
          a = MFMA(b1.v2, *(const short8v*)(wp + 10*32), a);
          a = MFMA(b1.v3, *(const short8v*)(wp + 11*32), a);
          a = MFMA(b1.v4, *(const short8v*)(wp + 12*32), a);
          a = MFMA(b1.v5, *(const short8v*)(wp + 13*32), a);
          a = MFMA(b1.v6, *(const short8v*)(wp + 14*32), a);
          a = MFMA(b1.v7, *(const short8v*)(wp + 15*32), a);
          if (tt < 64){
            const ushort* ip = i2aT + ncol*512 + kh*256 + ko;
            const ushort* xp = xb + (t*64 + arow)*512 + kh*256 + ko;
#pragma unroll
            for (int it = 0; it < 8; ++it)
              a = MFMA(*(const short8v*)(xp + it*32), *(const short8v*)(ip + it*32), a);
          }
          const int rb = strip*16 + ((lane >> 4) << 2);
#pragma unroll
          for (int r = 0; r < 4; ++r) lred[kh][rb + r][cc] = a[r];
          __syncthreads();
          for (int e = tid; e < 1024; e += 512){
            int row = e >> 4, c2 = e & 15;
            stg_f32(hyp + row*5120 + tt*16 + c2, lred[0][row][c2] + lred[1][row][c2]);
          }
          __syncthreads();
        }
      }
    }
    ++bu; gbar(barcnt, bu*NB);

    // ---------- Phase C: logits — grouped 4-deep prefetch ----------
    {
      const int b = bid >> 2;
      const int sg = ((bid & 3) << 3) + w;
      const float* qp = hyp + b*5120 + lane*16;
      const float* rp = r2a + lane*16;
      f32x4 q0v,q1v,q2v,q3v;
      ldg4f(qp, q0v, q1v, q2v, q3v);                          // mutable: bypass
      float q[16], r[16];
#pragma unroll
      for (int i = 0; i < 4; ++i){
        q[i]=q0v[i]; q[4+i]=q1v[i]; q[8+i]=q2v[i]; q[12+i]=q3v[i];
        float4 rv = ld4(rp + i*4);
        r[4*i]=rv.x; r[4*i+1]=rv.y; r[4*i+2]=rv.z; r[4*i+3]=rv.w;
      }
      const ushort* ppb = pcb + (sg*8*64 + b)*1024 + lane*16;
#pragma unroll
      for (int gq = 0; gq < 2; ++gq){
        uint4 va[4], vb[4];
#pragma unroll
        for (int pi = 0; pi < 4; ++pi){
          va[pi] = *(const uint4*)(ppb + (gq*4 + pi)*65536);
          vb[pi] = *(const uint4*)(ppb + (gq*4 + pi)*65536 + 8);
        }
#pragma unroll
        for (int pi = 0; pi < 4; ++pi){
          uint4 v0 = va[pi], v1 = vb[pi];
          float acc;
          acc  = tanhfast(u2f(v0.x << 16)              + q[0])  * r[0];
          acc  = fmaf(tanhfast(u2f(v0.x & 0xffff0000u) + q[1]),  r[1],  acc);
          acc  = fmaf(tanhfast(u2f(v0.y << 16)         + q[2]),  r[2],  acc);
          acc  = fmaf(tanhfast(u2f(v0.y & 0xffff0000u) + q[3]),  r[3],  acc);
          acc  = fmaf(tanhfast(u2f(v0.z << 16)         + q[4]),  r[4],  acc);
          acc  = fmaf(tanhfast(u2f(v0.z & 0xffff0000u) + q[5]),  r[5],  acc);
          acc  = fmaf(tanhfast(u2f(v0.w << 16)         + q[6]),  r[6],  acc);
          acc  = fmaf(tanhfast(u2f(v0.w & 0xffff0000u) + q[7]),  r[7],  acc);
          acc  = fmaf(tanhfast(u2f(v1.x << 16)         + q[8]),  r[8],  acc);
          acc  = fmaf(tanhfast(u2f(v1.x & 0xffff0000u) + q[9]),  r[9],  acc);
          acc  = fmaf(tanhfast(u2f(v1.y << 16)         + q[10]), r[10], acc);
          acc  = fmaf(tanhfast(u2f(v1.y & 0xffff0000u) + q[11]), r[11], acc);
          acc  = fmaf(tanhfast(u2f(v1.z << 16)         + q[12]), r[12], acc);
          acc  = fmaf(tanhfast(u2f(v1.z & 0xffff0000u) + q[13]), r[13], acc);
          acc  = fmaf(tanhfast(u2f(v1.w << 16)         + q[14]), r[14], acc);
          acc  = fmaf(tanhfast(u2f(v1.w & 0xffff0000u) + q[15]), r[15], acc);
#pragma unroll
          for (int off = 32; off; off >>= 1) acc += __shfl_xor(acc, off);
          if (lane == 0) stg_f32(logits + b*256 + sg*8 + gq*4 + pi, acc);
        }
      }
    }
    ++bu; gbar(barcnt, bu*NB);

    // ---------- Phase D: softmax + weighted ctx — grouped 8-deep prefetch ----------
    {
      const int b = bid >> 2, cq = bid & 3;
      if (tid < 256){
        float l = ldg1f(logits + b*256 + tid);                 // mutable: bypass
        red[tid] = l; al[tid] = l;
      }
      __syncthreads();
      for (int s = 128; s; s >>= 1){ if (tid < s) red[tid] = fmaxf(red[tid], red[tid+s]); __syncthreads(); }
      float mx = red[0]; __syncthreads();
      if (tid < 256){ float e = __expf(al[tid] - mx); al[tid] = e; red[tid] = e; }
      __syncthreads();
      for (int s = 128; s; s >>= 1){ if (tid < s) red[tid] += red[tid+s]; __syncthreads(); }
      float inv = rcpf_(red[0]);
      const int ci = tid & 63, sh = tid >> 6;
      const int c = cq*256 + ci*4;
      const ushort* cp = ctxb + (b*256 + sh*32)*1024 + c;      // read-only: cached
      float a0=0.f, a1=0.f, a2=0.f, a3=0.f;
#pragma unroll
      for (int g8 = 0; g8 < 4; ++g8){
        ushort4 vv[8];
#pragma unroll
        for (int s = 0; s < 8; ++s) vv[s] = *(const ushort4*)(cp + (g8*8 + s)*1024);
#pragma unroll
        for (int s = 0; s < 8; ++s){
          float aw = al[sh*32 + g8*8 + s];
          a0 = fmaf(aw, bf2f(vv[s].x), a0);
          a1 = fmaf(aw, bf2f(vv[s].y), a1);
          a2 = fmaf(aw, bf2f(vv[s].z), a2);
          a3 = fmaf(aw, bf2f(vv[s].w), a3);
        }
      }
      part4[sh][ci] = make_float4(a0, a1, a2, a3);
      __syncthreads();
      if (tid < 256){
        const float* pf = (const float*)part4;
        float s0 = 0.f;
#pragma unroll
        for (int s2 = 0; s2 < 8; ++s2) s0 += pf[s2*256 + tid];
        stg_u16(wctxbf + b*1024 + cq*256 + tid, (unsigned)f2bf(s0 * inv));
      }
    }
    ++bu; gbar(barcnt, bu*NB);

    // ---------- Phase E: gates2 (4 gates x 4 h-cols) + LSTM2 ----------
    {
      const int g = cc >> 2;
      const int ncol = (g << 10) + (bid << 2) + (cc & 3);
      const int arow = strip*16 + cc;
      const ushort* wp = w3b + ncol*1024 + kh*512 + ko;
      const ushort* ap = wctxbf + arow*1024 + kh*512 + ko;
      f32x4 a = {0.f,0.f,0.f,0.f};
      V8 b0 = ldg8(ap);                                       // mutable: bypass
      a = MFMA(b0.v0, *(const short8v*)(wp + 0*32), a);
      a = MFMA(b0.v1, *(const short8v*)(wp + 1*32), a);
      a = MFMA(b0.v2, *(const short8v*)(wp + 2*32), a);
      a = MFMA(b0.v3, *(const short8v*)(wp + 3*32), a);
      a = MFMA(b0.v4, *(const short8v*)(wp + 4*32), a);
      a = MFMA(b0.v5, *(const short8v*)(wp + 5*32), a);
      a = MFMA(b0.v6, *(const short8v*)(wp + 6*32), a);
      a = MFMA(b0.v7, *(const short8v*)(wp + 7*32), a);
      V8 b1 = ldg8(ap + 256);
      a = MFMA(b1.v0, *(const short8v*)(wp + 8*32), a);
      a = MFMA(b1.v1, *(const short8v*)(wp + 9*32), a);
      a = MFMA(b1.v2, *(const short8v*)(wp + 10*32), a);
      a = MFMA(b1.v3, *(const short8v*)(wp + 11*32), a);
      a = MFMA(b1.v4, *(const short8v*)(wp + 12*32), a);
      a = MFMA(b1.v5, *(const short8v*)(wp + 13*32), a);
      a = MFMA(b1.v6, *(const short8v*)(wp + 14*32), a);
      a = MFMA(b1.v7, *(const short8v*)(wp + 15*32), a);
      const int rb = strip*16 + ((lane >> 4) << 2);
#pragma unroll
      for (int r = 0; r < 4; ++r) lred[kh][rb + r][cc] = a[r];
    }
    __syncthreads();
    if (tid < 256){
      const int row = tid >> 2, hi = tid & 3, hh = (bid << 2) + hi;
      const float* gp = hyp + row*5120 + 1024 + hh;
      float ga, gb, gc, gd;
      ldg4s(gp, gp+1024, gp+2048, gp+3072, ga, gb, gc, gd);    // mutable: bypass
      float gi = lred[0][row][hi]      + lred[1][row][hi]      + ga + b2s[hh];
      float gf = lred[0][row][4+hi]    + lred[1][row][4+hi]    + gb + b2s[1024+hh];
      float gg = lred[0][row][8+hi]    + lred[1][row][8+hi]    + gc + b2s[2048+hh];
      float go = lred[0][row][12+hi]   + lred[1][row][12+hi]   + gd + b2s[3072+hh];
      float c2 = sigf(gf)*cym[row*1024+hh] + sigf(gi)*tanhfast(gg);
      float hv = sigf(go)*tanhfast(c2);
      out[t*65536 + row*1024 + hh] = hv;
      cxb[row*1024+hh] = c2;        // block-local: cached
      hxb[row*1024+hh] = hv;
      stg_u16(hxbbf + row*1024 + hh, (unsigned)f2bf(hv));
    }
    ++bu; gbar(barcnt, bu*NB);
  }
}

extern "C" void kernel_launch(void* const* d_in, const int* in_sizes, int n_in,
                              void* d_out, int out_size, void* d_ws, size_t ws_size,
                              hipStream_t stream) {
  const float* input = (const float*)d_in[0];
  const float* hx    = (const float*)d_in[1];
  const float* cx    = (const float*)d_in[2];
  const float* ctxp  = (const float*)d_in[3];
  const float* iw1   = (const float*)d_in[4];
  const float* hw1   = (const float*)d_in[5];
  const float* ib1   = (const float*)d_in[6];
  const float* hb1   = (const float*)d_in[7];
  const float* iw2   = (const float*)d_in[8];
  const float* hw2   = (const float*)d_in[9];
  const float* ib2   = (const float*)d_in[10];
  const float* hb2   = (const float*)d_in[11];
  const float* c2a   = (const float*)d_in[12];
  const float* b_c2a = (const float*)d_in[13];
  const float* h2a   = (const float*)d_in[14];
  const float* i2a   = (const float*)d_in[15];
  const float* r2a   = (const float*)d_in[16];
  float* out = (float*)d_out;

  char* base = (char*)d_ws;
  ushort* pcb    = (ushort*)(base);                     // 33,554,432
  ushort* ctxb   = (ushort*)(base + 33554432);          // 33,554,432
  ushort* xb     = (ushort*)(base + 67108864);          // 16,777,216
  ushort* w1b    = (ushort*)(base + 83886080);          // 12,582,912
  ushort* w2b    = (ushort*)(base + 96468992);          // 10,485,760
  ushort* w3b    = (ushort*)(base + 106954752);         //  8,388,608
  ushort* i2aT   = (ushort*)(base + 115343360);         //  1,048,576
  float*  hyp    = (float*)(base + 116391936);          //  1,310,720
  float*  cym    = (float*)(base + 117702656);          //    262,144
  float*  hxb    = (float*)(base + 117964800);          //    262,144
  float*  cxb    = (float*)(base + 118226944);          //    262,144
  ushort* hybf   = (ushort*)(base + 118489088);         //    131,072
  ushort* hxbbf  = (ushort*)(base + 118620160);         //    131,072
  ushort* wctxbf = (ushort*)(base + 118751232);         //    131,072
  float*  logits = (float*)(base + 118882304);          //     65,536
  float*  b1s    = (float*)(base + 118947840);          //     16,384
  float*  b2s    = (float*)(base + 118964224);          //     16,384
  unsigned* barcnt = (unsigned*)(base + 118980608);     //        256

  hipMemsetAsync(barcnt, 0, 256, stream);
  hipMemcpyAsync(hxb, hx, 262144, hipMemcpyDeviceToDevice, stream);
  hipMemcpyAsync(cxb, cx, 262144, hipMemcpyDeviceToDevice, stream);

  k_cvthx<<<64,   256, 0, stream>>>(hx, hxbbf);
  k_bias<<<16,    256, 0, stream>>>(ib1, hb1, ib2, hb2, b1s, b2s);
  k_w1  <<<6144,  256, 0, stream>>>(iw1, hw1, w1b);
  k_w2  <<<5120,  256, 0, stream>>>(h2a, hw2, w2b);
  k_w3  <<<4096,  256, 0, stream>>>(iw2, w3b);
  k_ctxT<<<16384, 256, 0, stream>>>(ctxp, ctxb);
  k_xb  <<<8192,  256, 0, stream>>>(input, xb);
  k_i2aT<<<2048,  256, 0, stream>>>(i2a, i2aT);
  k_pc  <<<dim3(256,16), 256, 0, stream>>>(ctxp, c2a, b_c2a, pcb);

  k_fused<<<NB, 512, 0, stream>>>(xb, w1b, w2b, w3b, i2aT, pcb, ctxb, r2a,
                                  b1s, b2s, hyp, cym, cxb, hxb, hybf, hxbbf,
                                  wctxbf, logits, out, barcnt);

  hipMemcpyAsync(out + 16777216,         hxb, 262144, hipMemcpyDeviceToDevice, stream);
  hipMemcpyAsync(out + 16777216 + 65536, cxb, 262144, hipMemcpyDeviceToDevice, stream);
}